// Round 1
// baseline (2431.920 us; speedup 1.0000x reference)
//
#include <hip/hip_runtime.h>

#define N_NODES 200000
#define H_EDGES 50000
#define D 64
#define NNZ 2000000

#define SCAN_BLOCK 256
#define SCAN_ELEMS 1024
#define NB_NNZ ((NNZ + 255) / 256)

__constant__ float kLeaky = 0.2f;

// ---------------- CSR build: counting sort ----------------

__global__ void hist_kernel(const int* __restrict__ keys, int* __restrict__ counts) {
    int i = blockIdx.x * 256 + threadIdx.x;
    if (i < NNZ) atomicAdd(&counts[keys[i]], 1);
}

__global__ void scan_reduce(const int* __restrict__ counts, int n, int* __restrict__ bsum) {
    __shared__ int sm[SCAN_BLOCK];
    int t = threadIdx.x;
    int base = blockIdx.x * SCAN_ELEMS + t * 4;
    int s = 0;
#pragma unroll
    for (int k = 0; k < 4; ++k) {
        int i = base + k;
        if (i < n) s += counts[i];
    }
    sm[t] = s;
    __syncthreads();
    for (int off = SCAN_BLOCK / 2; off > 0; off >>= 1) {
        if (t < off) sm[t] += sm[t + off];
        __syncthreads();
    }
    if (t == 0) bsum[blockIdx.x] = sm[0];
}

// exclusive-scan the per-block sums in place; also write row_ptr[n] = total
__global__ void scan_spine(int* __restrict__ bsum, int nb, int* __restrict__ row_ptr, int n) {
    __shared__ int sm[SCAN_BLOCK];
    int t = threadIdx.x;
    int v = (t < nb) ? bsum[t] : 0;
    sm[t] = v;
    __syncthreads();
    for (int off = 1; off < SCAN_BLOCK; off <<= 1) {
        int add = (t >= off) ? sm[t - off] : 0;
        __syncthreads();
        sm[t] += add;
        __syncthreads();
    }
    if (t < nb) bsum[t] = sm[t] - v;          // exclusive
    if (t == 0) row_ptr[n] = sm[SCAN_BLOCK - 1]; // total (padded lanes contribute 0)
}

__global__ void scan_write(const int* __restrict__ counts, int n, const int* __restrict__ boff,
                           int* __restrict__ row_ptr, int* __restrict__ cursor) {
    __shared__ int sm[SCAN_BLOCK];
    int t = threadIdx.x;
    int base = blockIdx.x * SCAN_ELEMS + t * 4;
    int c0 = (base + 0 < n) ? counts[base + 0] : 0;
    int c1 = (base + 1 < n) ? counts[base + 1] : 0;
    int c2 = (base + 2 < n) ? counts[base + 2] : 0;
    int c3 = (base + 3 < n) ? counts[base + 3] : 0;
    int s = c0 + c1 + c2 + c3;
    sm[t] = s;
    __syncthreads();
    for (int off = 1; off < SCAN_BLOCK; off <<= 1) {
        int add = (t >= off) ? sm[t - off] : 0;
        __syncthreads();
        sm[t] += add;
        __syncthreads();
    }
    int p = sm[t] - s + boff[blockIdx.x];
    if (base + 0 < n) { row_ptr[base + 0] = p; cursor[base + 0] = p; } p += c0;
    if (base + 1 < n) { row_ptr[base + 1] = p; cursor[base + 1] = p; } p += c1;
    if (base + 2 < n) { row_ptr[base + 2] = p; cursor[base + 2] = p; } p += c2;
    if (base + 3 < n) { row_ptr[base + 3] = p; cursor[base + 3] = p; }
}

__global__ void scatter_kernel(const int* __restrict__ keys, const int* __restrict__ other,
                               const float* __restrict__ vals, int* __restrict__ cursor,
                               int* __restrict__ out_idx, float* __restrict__ out_vals) {
    int i = blockIdx.x * 256 + threadIdx.x;
    if (i < NNZ) {
        int k = keys[i];
        int p = atomicAdd(&cursor[k], 1);
        out_idx[p] = other[i];
        out_vals[p] = vals[i];
    }
}

// ---------------- SpMM: one wave per output row (pull, no atomics) ----------------

__global__ void spmm_csr_kernel(const int* __restrict__ row_ptr, const int* __restrict__ idx,
                                const float* __restrict__ vals, const float* __restrict__ x,
                                float* __restrict__ y, int n_rows) {
    int row = blockIdx.x * 4 + (threadIdx.x >> 6);
    int lane = threadIdx.x & 63;
    if (row >= n_rows) return;
    int p0 = row_ptr[row];
    int p1 = row_ptr[row + 1];
    float acc = 0.f;
    for (int j = p0; j < p1; ++j) {
        int c = idx[j];
        float v = vals[j];
        acc = fmaf(v, x[c * D + lane], acc);
    }
    y[row * D + lane] = acc;
}

// ---------------- fallback: COO atomic SpMM (used only if ws too small) ----------------

__global__ void spmm_atomic_kernel(const int* __restrict__ keys, const int* __restrict__ other,
                                   const float* __restrict__ vals, const float* __restrict__ x,
                                   float* __restrict__ y) {
    long i = (long)blockIdx.x * 256 + threadIdx.x;
    int e = (int)(i >> 4);
    int sub = ((int)i & 15) * 4;
    if (e >= NNZ) return;
    int r = keys[e];
    int c = other[e];
    float v = vals[e];
    const float4 xv = *(const float4*)&x[c * D + sub];
    atomicAdd(&y[r * D + sub + 0], v * xv.x);
    atomicAdd(&y[r * D + sub + 1], v * xv.y);
    atomicAdd(&y[r * D + sub + 2], v * xv.z);
    atomicAdd(&y[r * D + sub + 3], v * xv.w);
}

// ---------------- fused leaky_relu + LayerNorm + residual (in place) ----------------

__global__ void fused_ln_kernel(float* __restrict__ h, const float* __restrict__ embs,
                                const float* __restrict__ gamma, const float* __restrict__ beta,
                                int n_rows, int apply_leaky) {
    int row = blockIdx.x * 4 + (threadIdx.x >> 6);
    int lane = threadIdx.x & 63;
    if (row >= n_rows) return;
    float v = h[row * D + lane];
    if (apply_leaky) v = (v > 0.f) ? v : 0.2f * v;
    float s = v;
    for (int off = 32; off > 0; off >>= 1) s += __shfl_xor(s, off, 64);
    float mu = s * (1.0f / D);
    float dd = v - mu;
    float q = dd * dd;
    for (int off = 32; off > 0; off >>= 1) q += __shfl_xor(q, off, 64);
    float var = q * (1.0f / D);
    h[row * D + lane] = dd * rsqrtf(var + 1e-5f) * gamma[lane] + beta[lane]
                        + embs[row * D + lane];
}

extern "C" void kernel_launch(void* const* d_in, const int* in_sizes, int n_in,
                              void* d_out, int out_size, void* d_ws, size_t ws_size,
                              hipStream_t stream) {
    const float* embs   = (const float*)d_in[0];
    const int*   A_rows = (const int*)d_in[1];
    const int*   A_cols = (const int*)d_in[2];
    const float* A_vals = (const float*)d_in[3];
    const int*   S_rows = (const int*)d_in[4];
    const int*   S_cols = (const int*)d_in[5];
    const float* S_vals = (const float*)d_in[6];
    const float* gamma  = (const float*)d_in[7];   // [2][64]
    const float* beta   = (const float*)d_in[8];   // [2][64]
    float* out = (float*)d_out;

    // ---- workspace layout ----
    size_t off = 0;
    auto bump = [&](size_t b) { size_t o = off; off += (b + 255) & ~(size_t)255; return o; };
    size_t o_B1    = bump((size_t)N_NODES * D * 4);
    size_t o_BH    = bump((size_t)H_EDGES * D * 4);
    size_t o_ptrAT = bump((size_t)(N_NODES + 1) * 4);
    size_t o_ptrST = bump((size_t)(H_EDGES + 1) * 4);
    size_t o_ptrS  = bump((size_t)(N_NODES + 1) * 4);
    size_t o_ptrA  = bump((size_t)(N_NODES + 1) * 4);
    size_t o_idx[4], o_val[4];
    for (int i = 0; i < 4; ++i) {
        o_idx[i] = bump((size_t)NNZ * 4);
        o_val[i] = bump((size_t)NNZ * 4);
    }
    size_t o_counts = bump((size_t)N_NODES * 4);
    size_t o_cursor = bump((size_t)N_NODES * 4);
    size_t o_bsum   = bump(4096);
    size_t needed_csr = off;

    char* w = (char*)d_ws;
    float* B1 = (float*)(w + o_B1);
    float* BH = (float*)(w + o_BH);
    int* ptrAT = (int*)(w + o_ptrAT);
    int* ptrST = (int*)(w + o_ptrST);
    int* ptrS  = (int*)(w + o_ptrS);
    int* ptrA  = (int*)(w + o_ptrA);
    int* idxb[4]; float* valb[4];
    for (int i = 0; i < 4; ++i) {
        idxb[i] = (int*)(w + o_idx[i]);
        valb[i] = (float*)(w + o_val[i]);
    }
    int* counts = (int*)(w + o_counts);
    int* cursor = (int*)(w + o_cursor);
    int* bsum   = (int*)(w + o_bsum);

    bool use_csr = (ws_size >= needed_csr);

    auto fused_ln = [&](float* h, int layer) {
        fused_ln_kernel<<<(N_NODES + 3) / 4, 256, 0, stream>>>(
            h, embs, gamma + layer * D, beta + layer * D, N_NODES, layer == 0 ? 1 : 0);
    };

    if (use_csr) {
        auto build = [&](const int* keys, const int* other, const float* vals, int n,
                         int* rp, int* oi, float* ov) {
            hipMemsetAsync(counts, 0, (size_t)n * 4, stream);
            hist_kernel<<<NB_NNZ, 256, 0, stream>>>(keys, counts);
            int nb = (n + SCAN_ELEMS - 1) / SCAN_ELEMS;
            scan_reduce<<<nb, SCAN_BLOCK, 0, stream>>>(counts, n, bsum);
            scan_spine<<<1, SCAN_BLOCK, 0, stream>>>(bsum, nb, rp, n);
            scan_write<<<nb, SCAN_BLOCK, 0, stream>>>(counts, n, bsum, rp, cursor);
            scatter_kernel<<<NB_NNZ, 256, 0, stream>>>(keys, other, vals, cursor, oi, ov);
        };

        // 4 directions: AT (group by A_cols), ST (by S_cols), S (by S_rows), A (by A_rows)
        build(A_cols, A_rows, A_vals, N_NODES, ptrAT, idxb[0], valb[0]);
        build(S_cols, S_rows, S_vals, H_EDGES, ptrST, idxb[1], valb[1]);
        build(S_rows, S_cols, S_vals, N_NODES, ptrS,  idxb[2], valb[2]);
        build(A_rows, A_cols, A_vals, N_NODES, ptrA,  idxb[3], valb[3]);

        auto spmm = [&](int* rp, int* oi, float* ov, const float* x, float* y, int n) {
            spmm_csr_kernel<<<(n + 3) / 4, 256, 0, stream>>>(rp, oi, ov, x, y, n);
        };

        for (int layer = 0; layer < 2; ++layer) {
            const float* xin = (layer == 0) ? embs : out;
            spmm(ptrAT, idxb[0], valb[0], xin, B1, N_NODES);  // t1 = A^T x   [N]
            spmm(ptrST, idxb[1], valb[1], B1,  BH, H_EDGES);  // t2 = S^T t1  [H]
            spmm(ptrS,  idxb[2], valb[2], BH,  B1, N_NODES);  // t3 = S t2    [N]
            spmm(ptrA,  idxb[3], valb[3], B1,  out, N_NODES); // t4 = A t3    [N]
            fused_ln(out, layer);
        }
    } else {
        // COO + atomics fallback (needs only B1 + BH = 64 MB)
        auto spmm_at = [&](const int* keys, const int* other, const float* vals,
                           const float* x, float* y, int n) {
            hipMemsetAsync(y, 0, (size_t)n * D * 4, stream);
            long threads = (long)NNZ * 16;
            int blocks = (int)((threads + 255) / 256);
            spmm_atomic_kernel<<<blocks, 256, 0, stream>>>(keys, other, vals, x, y);
        };
        for (int layer = 0; layer < 2; ++layer) {
            const float* xin = (layer == 0) ? embs : out;
            spmm_at(A_cols, A_rows, A_vals, xin, B1, N_NODES);
            spmm_at(S_cols, S_rows, S_vals, B1,  BH, H_EDGES);
            spmm_at(S_rows, S_cols, S_vals, BH,  B1, N_NODES);
            spmm_at(A_rows, A_cols, A_vals, B1,  out, N_NODES);
            fused_ln(out, layer);
        }
    }
}

// Round 2
// 1635.620 us; speedup vs baseline: 1.4868x; 1.4868x over previous
//
#include <hip/hip_runtime.h>

#define N_NODES 200000
#define H_EDGES 50000
#define D 64
#define NNZ 2000000

#define SCAN_BLOCK 256
#define SCAN_ELEMS 1024
#define NB_NNZ ((NNZ + 255) / 256)

// ---------------- CSR build: counting sort ----------------

__global__ void hist_kernel(const int* __restrict__ keys, int* __restrict__ counts) {
    int i = blockIdx.x * 256 + threadIdx.x;
    if (i < NNZ) atomicAdd(&counts[keys[i]], 1);
}

__global__ void scan_reduce(const int* __restrict__ counts, int n, int* __restrict__ bsum) {
    __shared__ int sm[SCAN_BLOCK];
    int t = threadIdx.x;
    int base = blockIdx.x * SCAN_ELEMS + t * 4;
    int s = 0;
#pragma unroll
    for (int k = 0; k < 4; ++k) {
        int i = base + k;
        if (i < n) s += counts[i];
    }
    sm[t] = s;
    __syncthreads();
    for (int off = SCAN_BLOCK / 2; off > 0; off >>= 1) {
        if (t < off) sm[t] += sm[t + off];
        __syncthreads();
    }
    if (t == 0) bsum[blockIdx.x] = sm[0];
}

// exclusive-scan the per-block sums in place; also write row_ptr[n] = total
__global__ void scan_spine(int* __restrict__ bsum, int nb, int* __restrict__ row_ptr, int n) {
    __shared__ int sm[SCAN_BLOCK];
    int t = threadIdx.x;
    int v = (t < nb) ? bsum[t] : 0;
    sm[t] = v;
    __syncthreads();
    for (int off = 1; off < SCAN_BLOCK; off <<= 1) {
        int add = (t >= off) ? sm[t - off] : 0;
        __syncthreads();
        sm[t] += add;
        __syncthreads();
    }
    if (t < nb) bsum[t] = sm[t] - v;          // exclusive
    if (t == 0) row_ptr[n] = sm[SCAN_BLOCK - 1]; // total (padded lanes contribute 0)
}

__global__ void scan_write(const int* __restrict__ counts, int n, const int* __restrict__ boff,
                           int* __restrict__ row_ptr, int* __restrict__ cursor) {
    __shared__ int sm[SCAN_BLOCK];
    int t = threadIdx.x;
    int base = blockIdx.x * SCAN_ELEMS + t * 4;
    int c0 = (base + 0 < n) ? counts[base + 0] : 0;
    int c1 = (base + 1 < n) ? counts[base + 1] : 0;
    int c2 = (base + 2 < n) ? counts[base + 2] : 0;
    int c3 = (base + 3 < n) ? counts[base + 3] : 0;
    int s = c0 + c1 + c2 + c3;
    sm[t] = s;
    __syncthreads();
    for (int off = 1; off < SCAN_BLOCK; off <<= 1) {
        int add = (t >= off) ? sm[t - off] : 0;
        __syncthreads();
        sm[t] += add;
        __syncthreads();
    }
    int p = sm[t] - s + boff[blockIdx.x];
    if (base + 0 < n) { row_ptr[base + 0] = p; cursor[base + 0] = p; } p += c0;
    if (base + 1 < n) { row_ptr[base + 1] = p; cursor[base + 1] = p; } p += c1;
    if (base + 2 < n) { row_ptr[base + 2] = p; cursor[base + 2] = p; } p += c2;
    if (base + 3 < n) { row_ptr[base + 3] = p; cursor[base + 3] = p; }
}

// scatter packed (other_idx, val_bits) int2 per edge
__global__ void scatter_kernel(const int* __restrict__ keys, const int* __restrict__ other,
                               const float* __restrict__ vals, int* __restrict__ cursor,
                               int2* __restrict__ out_ev) {
    int i = blockIdx.x * 256 + threadIdx.x;
    if (i < NNZ) {
        int k = keys[i];
        int p = atomicAdd(&cursor[k], 1);
        out_ev[p] = make_int2(other[i], __float_as_int(vals[i]));
    }
}

// ---------------- SpMM: half-wave (32 lanes, float2) per row, 4-deep unroll ----------------

__global__ void spmm_csr_kernel(const int* __restrict__ row_ptr, const int2* __restrict__ ev,
                                const float* __restrict__ x, float* __restrict__ y, int n_rows) {
    int row = blockIdx.x * 8 + (threadIdx.x >> 5);
    int l = threadIdx.x & 31;
    if (row >= n_rows) return;
    int p0 = row_ptr[row];
    int p1 = row_ptr[row + 1];
    float accx = 0.f, accy = 0.f;
    int j = p0;
    for (; j + 4 <= p1; j += 4) {
        int2 e0 = ev[j + 0];
        int2 e1 = ev[j + 1];
        int2 e2 = ev[j + 2];
        int2 e3 = ev[j + 3];
        float2 x0 = *(const float2*)&x[(e0.x << 6) + l * 2];
        float2 x1 = *(const float2*)&x[(e1.x << 6) + l * 2];
        float2 x2 = *(const float2*)&x[(e2.x << 6) + l * 2];
        float2 x3 = *(const float2*)&x[(e3.x << 6) + l * 2];
        float v0 = __int_as_float(e0.y);
        float v1 = __int_as_float(e1.y);
        float v2 = __int_as_float(e2.y);
        float v3 = __int_as_float(e3.y);
        accx = fmaf(v0, x0.x, accx); accy = fmaf(v0, x0.y, accy);
        accx = fmaf(v1, x1.x, accx); accy = fmaf(v1, x1.y, accy);
        accx = fmaf(v2, x2.x, accx); accy = fmaf(v2, x2.y, accy);
        accx = fmaf(v3, x3.x, accx); accy = fmaf(v3, x3.y, accy);
    }
    for (; j < p1; ++j) {
        int2 e = ev[j];
        float2 xv = *(const float2*)&x[(e.x << 6) + l * 2];
        float v = __int_as_float(e.y);
        accx = fmaf(v, xv.x, accx); accy = fmaf(v, xv.y, accy);
    }
    *(float2*)&y[(row << 6) + l * 2] = make_float2(accx, accy);
}

// ---------------- fallback: COO atomic SpMM (used only if ws too small) ----------------

__global__ void spmm_atomic_kernel(const int* __restrict__ keys, const int* __restrict__ other,
                                   const float* __restrict__ vals, const float* __restrict__ x,
                                   float* __restrict__ y) {
    long i = (long)blockIdx.x * 256 + threadIdx.x;
    int e = (int)(i >> 4);
    int sub = ((int)i & 15) * 4;
    if (e >= NNZ) return;
    int r = keys[e];
    int c = other[e];
    float v = vals[e];
    const float4 xv = *(const float4*)&x[c * D + sub];
    atomicAdd(&y[r * D + sub + 0], v * xv.x);
    atomicAdd(&y[r * D + sub + 1], v * xv.y);
    atomicAdd(&y[r * D + sub + 2], v * xv.z);
    atomicAdd(&y[r * D + sub + 3], v * xv.w);
}

// ---------------- fused leaky_relu + LayerNorm + residual (in place) ----------------

__global__ void fused_ln_kernel(float* __restrict__ h, const float* __restrict__ embs,
                                const float* __restrict__ gamma, const float* __restrict__ beta,
                                int n_rows, int apply_leaky) {
    int row = blockIdx.x * 4 + (threadIdx.x >> 6);
    int lane = threadIdx.x & 63;
    if (row >= n_rows) return;
    float v = h[row * D + lane];
    if (apply_leaky) v = (v > 0.f) ? v : 0.2f * v;
    float s = v;
    for (int off = 32; off > 0; off >>= 1) s += __shfl_xor(s, off, 64);
    float mu = s * (1.0f / D);
    float dd = v - mu;
    float q = dd * dd;
    for (int off = 32; off > 0; off >>= 1) q += __shfl_xor(q, off, 64);
    float var = q * (1.0f / D);
    h[row * D + lane] = dd * rsqrtf(var + 1e-5f) * gamma[lane] + beta[lane]
                        + embs[row * D + lane];
}

extern "C" void kernel_launch(void* const* d_in, const int* in_sizes, int n_in,
                              void* d_out, int out_size, void* d_ws, size_t ws_size,
                              hipStream_t stream) {
    const float* embs   = (const float*)d_in[0];
    const int*   A_rows = (const int*)d_in[1];
    const int*   A_cols = (const int*)d_in[2];
    const float* A_vals = (const float*)d_in[3];
    const int*   S_rows = (const int*)d_in[4];
    const int*   S_cols = (const int*)d_in[5];
    const float* S_vals = (const float*)d_in[6];
    const float* gamma  = (const float*)d_in[7];   // [2][64]
    const float* beta   = (const float*)d_in[8];   // [2][64]
    float* out = (float*)d_out;

    // ---- workspace layout ----
    size_t off = 0;
    auto bump = [&](size_t b) { size_t o = off; off += (b + 255) & ~(size_t)255; return o; };
    size_t o_B1    = bump((size_t)N_NODES * D * 4);
    size_t o_BH    = bump((size_t)H_EDGES * D * 4);
    size_t o_ptrAT = bump((size_t)(N_NODES + 1) * 4);
    size_t o_ptrST = bump((size_t)(H_EDGES + 1) * 4);
    size_t o_ptrS  = bump((size_t)(N_NODES + 1) * 4);
    size_t o_ptrA  = bump((size_t)(N_NODES + 1) * 4);
    size_t o_ev[4];
    for (int i = 0; i < 4; ++i) o_ev[i] = bump((size_t)NNZ * 8);
    size_t o_counts = bump((size_t)N_NODES * 4);
    size_t o_cursor = bump((size_t)N_NODES * 4);
    size_t o_bsum   = bump(4096);
    size_t needed_csr = off;

    char* w = (char*)d_ws;
    float* B1 = (float*)(w + o_B1);
    float* BH = (float*)(w + o_BH);
    int* ptrAT = (int*)(w + o_ptrAT);
    int* ptrST = (int*)(w + o_ptrST);
    int* ptrS  = (int*)(w + o_ptrS);
    int* ptrA  = (int*)(w + o_ptrA);
    int2* evb[4];
    for (int i = 0; i < 4; ++i) evb[i] = (int2*)(w + o_ev[i]);
    int* counts = (int*)(w + o_counts);
    int* cursor = (int*)(w + o_cursor);
    int* bsum   = (int*)(w + o_bsum);

    bool use_csr = (ws_size >= needed_csr);

    auto fused_ln = [&](float* h, int layer) {
        fused_ln_kernel<<<(N_NODES + 3) / 4, 256, 0, stream>>>(
            h, embs, gamma + layer * D, beta + layer * D, N_NODES, layer == 0 ? 1 : 0);
    };

    if (use_csr) {
        auto build = [&](const int* keys, const int* other, const float* vals, int n,
                         int* rp, int2* ev) {
            hipMemsetAsync(counts, 0, (size_t)n * 4, stream);
            hist_kernel<<<NB_NNZ, 256, 0, stream>>>(keys, counts);
            int nb = (n + SCAN_ELEMS - 1) / SCAN_ELEMS;
            scan_reduce<<<nb, SCAN_BLOCK, 0, stream>>>(counts, n, bsum);
            scan_spine<<<1, SCAN_BLOCK, 0, stream>>>(bsum, nb, rp, n);
            scan_write<<<nb, SCAN_BLOCK, 0, stream>>>(counts, n, bsum, rp, cursor);
            scatter_kernel<<<NB_NNZ, 256, 0, stream>>>(keys, other, vals, cursor, ev);
        };

        // 4 directions: AT (group by A_cols), ST (by S_cols), S (by S_rows), A (by A_rows)
        build(A_cols, A_rows, A_vals, N_NODES, ptrAT, evb[0]);
        build(S_cols, S_rows, S_vals, H_EDGES, ptrST, evb[1]);
        build(S_rows, S_cols, S_vals, N_NODES, ptrS,  evb[2]);
        build(A_rows, A_cols, A_vals, N_NODES, ptrA,  evb[3]);

        auto spmm = [&](int* rp, int2* ev, const float* x, float* y, int n) {
            spmm_csr_kernel<<<(n + 7) / 8, 256, 0, stream>>>(rp, ev, x, y, n);
        };

        for (int layer = 0; layer < 2; ++layer) {
            const float* xin = (layer == 0) ? embs : out;
            spmm(ptrAT, evb[0], xin, B1, N_NODES);  // t1 = A^T x   [N]
            spmm(ptrST, evb[1], B1,  BH, H_EDGES);  // t2 = S^T t1  [H]
            spmm(ptrS,  evb[2], BH,  B1, N_NODES);  // t3 = S t2    [N]
            spmm(ptrA,  evb[3], B1,  out, N_NODES); // t4 = A t3    [N]
            fused_ln(out, layer);
        }
    } else {
        // COO + atomics fallback (needs only B1 + BH = 64 MB)
        auto spmm_at = [&](const int* keys, const int* other, const float* vals,
                           const float* x, float* y, int n) {
            hipMemsetAsync(y, 0, (size_t)n * D * 4, stream);
            long threads = (long)NNZ * 16;
            int blocks = (int)((threads + 255) / 256);
            spmm_atomic_kernel<<<blocks, 256, 0, stream>>>(keys, other, vals, x, y);
        };
        for (int layer = 0; layer < 2; ++layer) {
            const float* xin = (layer == 0) ? embs : out;
            spmm_at(A_cols, A_rows, A_vals, xin, B1, N_NODES);
            spmm_at(S_cols, S_rows, S_vals, B1,  BH, H_EDGES);
            spmm_at(S_rows, S_cols, S_vals, BH,  B1, N_NODES);
            spmm_at(A_rows, A_cols, A_vals, B1,  out, N_NODES);
            fused_ln(out, layer);
        }
    }
}

// Round 3
// 1153.995 us; speedup vs baseline: 2.1074x; 1.4174x over previous
//
#include <hip/hip_runtime.h>

#define N_NODES 200000
#define H_EDGES 50000
#define D 64
#define NNZ 2000000

#define BS 256
#define EPB 12
#define EDGES_PER_BLOCK (EPB * BS)                       // 3072
#define NBLK ((NNZ + EDGES_PER_BLOCK - 1) / EDGES_PER_BLOCK)  // 652
#define NB_MAX 784
#define STAGE_B 6144

// ---------------- pass 0: per-bucket histogram ----------------

__global__ void bucket_hist(const int* __restrict__ keys, int* __restrict__ bcount,
                            int NB, int SH) {
    __shared__ int sh[NB_MAX];
    int t = threadIdx.x;
    for (int i = t; i < NB; i += BS) sh[i] = 0;
    __syncthreads();
    int blkbase = blockIdx.x * EDGES_PER_BLOCK;
#pragma unroll
    for (int k = 0; k < EPB; ++k) {
        int e = blkbase + k * BS + t;
        if (e < NNZ) atomicAdd(&sh[keys[e] >> SH], 1);
    }
    __syncthreads();
    for (int i = t; i < NB; i += BS) if (sh[i]) atomicAdd(&bcount[i], sh[i]);
}

// ---------------- spine: exclusive scan of bucket counts ----------------

__global__ void bucket_spine(const int* __restrict__ bcount, int* __restrict__ bbase,
                             int* __restrict__ gcur, int NB) {
    __shared__ int tmp[BS];
    int t = threadIdx.x;
    int c[4]; int s = 0;
#pragma unroll
    for (int j = 0; j < 4; ++j) { int i = t * 4 + j; c[j] = (i < NB) ? bcount[i] : 0; s += c[j]; }
    tmp[t] = s;
    __syncthreads();
    for (int off = 1; off < BS; off <<= 1) {
        int v = (t >= off) ? tmp[t - off] : 0;
        __syncthreads();
        tmp[t] += v;
        __syncthreads();
    }
    int base = tmp[t] - s;
#pragma unroll
    for (int j = 0; j < 4; ++j) {
        int i = t * 4 + j;
        if (i < NB) { bbase[i] = base; gcur[i] = base; base += c[j]; }
    }
}

// ---------------- pass A: LDS-staged bucket scatter (coalesced runs) ----------------

__global__ void bucket_scatter(const int* __restrict__ keys, const int* __restrict__ other,
                               const float* __restrict__ vals, int* __restrict__ gcur,
                               int4* __restrict__ ev4, int NB, int SH) {
    __shared__ int s_hist[NB_MAX];   // counts -> local starts (in place)
    __shared__ int s_garr[NB_MAX];   // reserved global starts
    __shared__ int s_tmp[BS];
    __shared__ int s_k[EDGES_PER_BLOCK];
    __shared__ int s_o[EDGES_PER_BLOCK];
    __shared__ int s_v[EDGES_PER_BLOCK];
    __shared__ int s_d[EDGES_PER_BLOCK];
    int t = threadIdx.x;
    int blkbase = blockIdx.x * EDGES_PER_BLOCK;
    int tot = min(EDGES_PER_BLOCK, NNZ - blkbase);
    for (int i = t; i < NB; i += BS) s_hist[i] = 0;
    __syncthreads();
    int bkt[EPB], rnk[EPB];
#pragma unroll
    for (int k = 0; k < EPB; ++k) {
        int e = blkbase + k * BS + t;
        if (e < NNZ) {
            int b = keys[e] >> SH;
            bkt[k] = b;
            rnk[k] = atomicAdd(&s_hist[b], 1);
        } else bkt[k] = -1;
    }
    __syncthreads();
    // exclusive scan of s_hist into local starts; reserve global ranges
    int c[4], pre[4]; int ssum = 0;
#pragma unroll
    for (int j = 0; j < 4; ++j) {
        int i = t * 4 + j;
        c[j] = (i < NB) ? s_hist[i] : 0;
        pre[j] = ssum; ssum += c[j];
    }
    s_tmp[t] = ssum;
    __syncthreads();
    for (int off = 1; off < BS; off <<= 1) {
        int v = (t >= off) ? s_tmp[t - off] : 0;
        __syncthreads();
        s_tmp[t] += v;
        __syncthreads();
    }
    int ebase = s_tmp[t] - ssum;
#pragma unroll
    for (int j = 0; j < 4; ++j) {
        int i = t * 4 + j;
        if (i < NB) {
            s_hist[i] = ebase + pre[j];
            if (c[j] > 0) s_garr[i] = atomicAdd(&gcur[i], c[j]);
        }
    }
    __syncthreads();
    // stage edges grouped by bucket
#pragma unroll
    for (int k = 0; k < EPB; ++k) {
        if (bkt[k] < 0) continue;
        int e = blkbase + k * BS + t;
        int p = s_hist[bkt[k]] + rnk[k];
        s_k[p] = keys[e];
        s_o[p] = other[e];
        s_v[p] = __float_as_int(vals[e]);
        s_d[p] = s_garr[bkt[k]] + rnk[k];
    }
    __syncthreads();
    for (int i = t; i < tot; i += BS)
        ev4[s_d[i]] = make_int4(s_k[i], s_o[i], s_v[i], 0);
}

// ---------------- pass B: per-bucket counting sort + row_ptr ----------------

__global__ void bucket_sort(const int4* __restrict__ ev4, const int* __restrict__ bbase,
                            const int* __restrict__ bcount, int2* __restrict__ ev,
                            int* __restrict__ row_ptr, int n, int NB, int SH) {
    __shared__ int s_cnt[BS + 1];
    __shared__ int s_cur[BS];
    __shared__ int2 s_ev[STAGE_B];
    int b = blockIdx.x;
    int t = threadIdx.x;
    int base = bbase[b];
    int cnt = bcount[b];
    int kb = b << SH;
    int span = min(1 << SH, n - kb);
    s_cnt[t] = 0;
    __syncthreads();
    for (int i = t; i < cnt; i += BS)
        atomicAdd(&s_cnt[ev4[base + i].x - kb], 1);
    __syncthreads();
    int c = s_cnt[t];
    for (int off = 1; off < BS; off <<= 1) {
        int v = (t >= off) ? s_cnt[t - off] : 0;
        __syncthreads();
        s_cnt[t] += v;
        __syncthreads();
    }
    int lstart = s_cnt[t] - c;   // exclusive prefix
    if (t < span) row_ptr[kb + t] = base + lstart;
    if (b == NB - 1 && t == 0) row_ptr[n] = NNZ;
    s_cur[t] = lstart;
    __syncthreads();
    for (int i = t; i < cnt; i += BS) {
        int4 e = ev4[base + i];
        int r = atomicAdd(&s_cur[e.x - kb], 1);
        int2 o = make_int2(e.y, e.z);
        if (r < STAGE_B) s_ev[r] = o; else ev[base + r] = o;
    }
    __syncthreads();
    int lim = min(cnt, STAGE_B);
    for (int i = t; i < lim; i += BS) ev[base + i] = s_ev[i];
}

// ---------------- SpMM: half-wave (32 lanes, float2) per row, 4-deep unroll ----------------

__global__ void spmm_csr_kernel(const int* __restrict__ row_ptr, const int2* __restrict__ ev,
                                const float* __restrict__ x, float* __restrict__ y, int n_rows) {
    int row = blockIdx.x * 8 + (threadIdx.x >> 5);
    int l = threadIdx.x & 31;
    if (row >= n_rows) return;
    int p0 = row_ptr[row];
    int p1 = row_ptr[row + 1];
    float accx = 0.f, accy = 0.f;
    int j = p0;
    for (; j + 4 <= p1; j += 4) {
        int2 e0 = ev[j + 0];
        int2 e1 = ev[j + 1];
        int2 e2 = ev[j + 2];
        int2 e3 = ev[j + 3];
        float2 x0 = *(const float2*)&x[(e0.x << 6) + l * 2];
        float2 x1 = *(const float2*)&x[(e1.x << 6) + l * 2];
        float2 x2 = *(const float2*)&x[(e2.x << 6) + l * 2];
        float2 x3 = *(const float2*)&x[(e3.x << 6) + l * 2];
        float v0 = __int_as_float(e0.y);
        float v1 = __int_as_float(e1.y);
        float v2 = __int_as_float(e2.y);
        float v3 = __int_as_float(e3.y);
        accx = fmaf(v0, x0.x, accx); accy = fmaf(v0, x0.y, accy);
        accx = fmaf(v1, x1.x, accx); accy = fmaf(v1, x1.y, accy);
        accx = fmaf(v2, x2.x, accx); accy = fmaf(v2, x2.y, accy);
        accx = fmaf(v3, x3.x, accx); accy = fmaf(v3, x3.y, accy);
    }
    for (; j < p1; ++j) {
        int2 e = ev[j];
        float2 xv = *(const float2*)&x[(e.x << 6) + l * 2];
        float v = __int_as_float(e.y);
        accx = fmaf(v, xv.x, accx); accy = fmaf(v, xv.y, accy);
    }
    *(float2*)&y[(row << 6) + l * 2] = make_float2(accx, accy);
}

// ---------------- fallback: COO atomic SpMM (used only if ws too small) ----------------

__global__ void spmm_atomic_kernel(const int* __restrict__ keys, const int* __restrict__ other,
                                   const float* __restrict__ vals, const float* __restrict__ x,
                                   float* __restrict__ y) {
    long i = (long)blockIdx.x * 256 + threadIdx.x;
    int e = (int)(i >> 4);
    int sub = ((int)i & 15) * 4;
    if (e >= NNZ) return;
    int r = keys[e];
    int c = other[e];
    float v = vals[e];
    const float4 xv = *(const float4*)&x[c * D + sub];
    atomicAdd(&y[r * D + sub + 0], v * xv.x);
    atomicAdd(&y[r * D + sub + 1], v * xv.y);
    atomicAdd(&y[r * D + sub + 2], v * xv.z);
    atomicAdd(&y[r * D + sub + 3], v * xv.w);
}

// ---------------- fused leaky_relu + LayerNorm + residual (in place) ----------------

__global__ void fused_ln_kernel(float* __restrict__ h, const float* __restrict__ embs,
                                const float* __restrict__ gamma, const float* __restrict__ beta,
                                int n_rows, int apply_leaky) {
    int row = blockIdx.x * 4 + (threadIdx.x >> 6);
    int lane = threadIdx.x & 63;
    if (row >= n_rows) return;
    float v = h[row * D + lane];
    if (apply_leaky) v = (v > 0.f) ? v : 0.2f * v;
    float s = v;
    for (int off = 32; off > 0; off >>= 1) s += __shfl_xor(s, off, 64);
    float mu = s * (1.0f / D);
    float dd = v - mu;
    float q = dd * dd;
    for (int off = 32; off > 0; off >>= 1) q += __shfl_xor(q, off, 64);
    float var = q * (1.0f / D);
    h[row * D + lane] = dd * rsqrtf(var + 1e-5f) * gamma[lane] + beta[lane]
                        + embs[row * D + lane];
}

extern "C" void kernel_launch(void* const* d_in, const int* in_sizes, int n_in,
                              void* d_out, int out_size, void* d_ws, size_t ws_size,
                              hipStream_t stream) {
    const float* embs   = (const float*)d_in[0];
    const int*   A_rows = (const int*)d_in[1];
    const int*   A_cols = (const int*)d_in[2];
    const float* A_vals = (const float*)d_in[3];
    const int*   S_rows = (const int*)d_in[4];
    const int*   S_cols = (const int*)d_in[5];
    const float* S_vals = (const float*)d_in[6];
    const float* gamma  = (const float*)d_in[7];   // [2][64]
    const float* beta   = (const float*)d_in[8];   // [2][64]
    float* out = (float*)d_out;

    // ---- workspace layout ----
    size_t off = 0;
    auto bump = [&](size_t b) { size_t o = off; off += (b + 255) & ~(size_t)255; return o; };
    size_t o_B1    = bump((size_t)N_NODES * D * 4);   // also hosts ev4 scratch (32MB < 51.2MB)
    size_t o_BH    = bump((size_t)H_EDGES * D * 4);
    size_t o_ptrAT = bump((size_t)(N_NODES + 1) * 4);
    size_t o_ptrST = bump((size_t)(H_EDGES + 1) * 4);
    size_t o_ptrS  = bump((size_t)(N_NODES + 1) * 4);
    size_t o_ptrA  = bump((size_t)(N_NODES + 1) * 4);
    size_t o_ev[4];
    for (int i = 0; i < 4; ++i) o_ev[i] = bump((size_t)NNZ * 8);
    size_t o_bcount = bump(NB_MAX * 4);
    size_t o_bbase  = bump(NB_MAX * 4);
    size_t o_gcur   = bump(NB_MAX * 4);
    size_t needed_csr = off;

    char* w = (char*)d_ws;
    float* B1 = (float*)(w + o_B1);
    int4* ev4 = (int4*)(w + o_B1);     // aliases B1 (build phase only)
    float* BH = (float*)(w + o_BH);
    int* ptrAT = (int*)(w + o_ptrAT);
    int* ptrST = (int*)(w + o_ptrST);
    int* ptrS  = (int*)(w + o_ptrS);
    int* ptrA  = (int*)(w + o_ptrA);
    int2* evb[4];
    for (int i = 0; i < 4; ++i) evb[i] = (int2*)(w + o_ev[i]);
    int* bcount = (int*)(w + o_bcount);
    int* bbase  = (int*)(w + o_bbase);
    int* gcur   = (int*)(w + o_gcur);

    bool use_csr = (ws_size >= needed_csr);

    auto fused_ln = [&](float* h, int layer) {
        fused_ln_kernel<<<(N_NODES + 3) / 4, 256, 0, stream>>>(
            h, embs, gamma + layer * D, beta + layer * D, N_NODES, layer == 0 ? 1 : 0);
    };

    if (use_csr) {
        auto build = [&](const int* keys, const int* other, const float* vals, int n, int SH,
                         int* rp, int2* ev) {
            int NB = (n + (1 << SH) - 1) >> SH;   // 782 for both N/SH=8 and H/SH=6
            hipMemsetAsync(bcount, 0, (size_t)NB * 4, stream);
            bucket_hist<<<NBLK, BS, 0, stream>>>(keys, bcount, NB, SH);
            bucket_spine<<<1, BS, 0, stream>>>(bcount, bbase, gcur, NB);
            bucket_scatter<<<NBLK, BS, 0, stream>>>(keys, other, vals, gcur, ev4, NB, SH);
            bucket_sort<<<NB, BS, 0, stream>>>(ev4, bbase, bcount, ev, rp, n, NB, SH);
        };

        // 4 directions: AT (group by A_cols), ST (by S_cols), S (by S_rows), A (by A_rows)
        build(A_cols, A_rows, A_vals, N_NODES, 8, ptrAT, evb[0]);
        build(S_cols, S_rows, S_vals, H_EDGES, 6, ptrST, evb[1]);
        build(S_rows, S_cols, S_vals, N_NODES, 8, ptrS,  evb[2]);
        build(A_rows, A_cols, A_vals, N_NODES, 8, ptrA,  evb[3]);

        auto spmm = [&](int* rp, int2* ev, const float* x, float* y, int n) {
            spmm_csr_kernel<<<(n + 7) / 8, 256, 0, stream>>>(rp, ev, x, y, n);
        };

        for (int layer = 0; layer < 2; ++layer) {
            const float* xin = (layer == 0) ? embs : out;
            spmm(ptrAT, evb[0], xin, B1, N_NODES);  // t1 = A^T x   [N]
            spmm(ptrST, evb[1], B1,  BH, H_EDGES);  // t2 = S^T t1  [H]
            spmm(ptrS,  evb[2], BH,  B1, N_NODES);  // t3 = S t2    [N]
            spmm(ptrA,  evb[3], B1,  out, N_NODES); // t4 = A t3    [N]
            fused_ln(out, layer);
        }
    } else {
        // COO + atomics fallback (needs only B1 + BH = 64 MB)
        auto spmm_at = [&](const int* keys, const int* other, const float* vals,
                           const float* x, float* y, int n) {
            hipMemsetAsync(y, 0, (size_t)n * D * 4, stream);
            long threads = (long)NNZ * 16;
            int blocks = (int)((threads + 255) / 256);
            spmm_atomic_kernel<<<blocks, 256, 0, stream>>>(keys, other, vals, x, y);
        };
        for (int layer = 0; layer < 2; ++layer) {
            const float* xin = (layer == 0) ? embs : out;
            spmm_at(A_cols, A_rows, A_vals, xin, B1, N_NODES);
            spmm_at(S_cols, S_rows, S_vals, B1,  BH, H_EDGES);
            spmm_at(S_rows, S_cols, S_vals, BH,  B1, N_NODES);
            spmm_at(A_rows, A_cols, A_vals, B1,  out, N_NODES);
            fused_ln(out, layer);
        }
    }
}

// Round 4
// 809.900 us; speedup vs baseline: 3.0027x; 1.4249x over previous
//
#include <hip/hip_runtime.h>
#include <hip/hip_fp16.h>

#define N_NODES 200000
#define H_EDGES 50000
#define D 64
#define NNZ 2000000

#define BS 256
#define EPB 12
#define EDGES_PER_BLOCK (EPB * BS)                            // 3072
#define NBLK ((NNZ + EDGES_PER_BLOCK - 1) / EDGES_PER_BLOCK)  // 652
#define NB 782        // bucket count: ceil(200000/256) == ceil(50000/64) == 782
#define NB_MAX 784
#define STAGE_B 6144

// problem p: 0 = A^T (keys A_cols), 1 = S^T (keys S_cols, SH=6), 2 = S (keys S_rows), 3 = A (keys A_rows)
__device__ __forceinline__ int prob_sh(int p) { return (p == 1) ? 6 : 8; }
__device__ __forceinline__ int prob_n(int p)  { return (p == 1) ? H_EDGES : N_NODES; }

// ---------------- build pass 0: per-bucket histogram (4 problems in one grid) ----------------

__global__ void hist4(const int* __restrict__ k0, const int* __restrict__ k1,
                      const int* __restrict__ k2, const int* __restrict__ k3,
                      int* __restrict__ bcount) {
    __shared__ int sh_[NB_MAX];
    int t = threadIdx.x;
    int p = blockIdx.x / NBLK;
    int lb = blockIdx.x % NBLK;
    const int* keys = (p == 0) ? k0 : (p == 1) ? k1 : (p == 2) ? k2 : k3;
    int SH = prob_sh(p);
    for (int i = t; i < NB; i += BS) sh_[i] = 0;
    __syncthreads();
    int base = lb * EDGES_PER_BLOCK;
#pragma unroll
    for (int k = 0; k < EPB; ++k) {
        int e = base + k * BS + t;
        if (e < NNZ) atomicAdd(&sh_[keys[e] >> SH], 1);
    }
    __syncthreads();
    int* bc = bcount + p * NB_MAX;
    for (int i = t; i < NB; i += BS) if (sh_[i]) atomicAdd(&bc[i], sh_[i]);
}

// ---------------- build spine: per-problem exclusive scan ----------------

__global__ void spine4(const int* __restrict__ bcount, int* __restrict__ bbase,
                       int* __restrict__ gcur) {
    __shared__ int tmp[BS];
    int p = blockIdx.x, t = threadIdx.x;
    const int* bc = bcount + p * NB_MAX;
    int c[4]; int s = 0;
#pragma unroll
    for (int j = 0; j < 4; ++j) { int i = t * 4 + j; c[j] = (i < NB) ? bc[i] : 0; s += c[j]; }
    tmp[t] = s;
    __syncthreads();
    for (int off = 1; off < BS; off <<= 1) {
        int v = (t >= off) ? tmp[t - off] : 0;
        __syncthreads();
        tmp[t] += v;
        __syncthreads();
    }
    int base = tmp[t] - s;
#pragma unroll
    for (int j = 0; j < 4; ++j) {
        int i = t * 4 + j;
        if (i < NB) { bbase[p * NB_MAX + i] = base; gcur[p * NB_MAX + i] = base; base += c[j]; }
    }
}

// ---------------- build pass A: LDS-staged bucket scatter -> ev (int2) + keyb ----------------

__global__ void scatter4(const int* k0, const int* o0, const float* v0_,
                         const int* k1, const int* o1, const float* v1_,
                         const int* k2, const int* o2, const float* v2_,
                         const int* k3, const int* o3, const float* v3_,
                         int* __restrict__ gcur,
                         int2* e0, int2* e1, int2* e2, int2* e3,
                         int* y0, int* y1, int* y2, int* y3) {
    __shared__ int s_hist[NB_MAX];
    __shared__ int s_garr[NB_MAX];
    __shared__ int s_tmp[BS];
    __shared__ int s_k[EDGES_PER_BLOCK];
    __shared__ int s_o[EDGES_PER_BLOCK];
    __shared__ int s_v[EDGES_PER_BLOCK];
    __shared__ int s_d[EDGES_PER_BLOCK];
    int t = threadIdx.x;
    int p = blockIdx.x / NBLK;
    int lb = blockIdx.x % NBLK;
    const int*   keys  = (p == 0) ? k0 : (p == 1) ? k1 : (p == 2) ? k2 : k3;
    const int*   other = (p == 0) ? o0 : (p == 1) ? o1 : (p == 2) ? o2 : o3;
    const float* vals  = (p == 0) ? v0_ : (p == 1) ? v1_ : (p == 2) ? v2_ : v3_;
    int2* ev   = (p == 0) ? e0 : (p == 1) ? e1 : (p == 2) ? e2 : e3;
    int*  keyb = (p == 0) ? y0 : (p == 1) ? y1 : (p == 2) ? y2 : y3;
    int SH = prob_sh(p);
    int* gc = gcur + p * NB_MAX;

    int blkbase = lb * EDGES_PER_BLOCK;
    int tot = min(EDGES_PER_BLOCK, NNZ - blkbase);
    for (int i = t; i < NB; i += BS) s_hist[i] = 0;
    __syncthreads();
    int bkt[EPB], rnk[EPB];
#pragma unroll
    for (int k = 0; k < EPB; ++k) {
        int e = blkbase + k * BS + t;
        if (e < NNZ) {
            int b = keys[e] >> SH;
            bkt[k] = b;
            rnk[k] = atomicAdd(&s_hist[b], 1);
        } else bkt[k] = -1;
    }
    __syncthreads();
    int c[4], pre[4]; int ssum = 0;
#pragma unroll
    for (int j = 0; j < 4; ++j) {
        int i = t * 4 + j;
        c[j] = (i < NB) ? s_hist[i] : 0;
        pre[j] = ssum; ssum += c[j];
    }
    s_tmp[t] = ssum;
    __syncthreads();
    for (int off = 1; off < BS; off <<= 1) {
        int v = (t >= off) ? s_tmp[t - off] : 0;
        __syncthreads();
        s_tmp[t] += v;
        __syncthreads();
    }
    int ebase = s_tmp[t] - ssum;
#pragma unroll
    for (int j = 0; j < 4; ++j) {
        int i = t * 4 + j;
        if (i < NB) {
            s_hist[i] = ebase + pre[j];
            if (c[j] > 0) s_garr[i] = atomicAdd(&gc[i], c[j]);
        }
    }
    __syncthreads();
#pragma unroll
    for (int k = 0; k < EPB; ++k) {
        if (bkt[k] < 0) continue;
        int e = blkbase + k * BS + t;
        int pp = s_hist[bkt[k]] + rnk[k];
        s_k[pp] = keys[e];
        s_o[pp] = other[e];
        s_v[pp] = __float_as_int(vals[e]);
        s_d[pp] = s_garr[bkt[k]] + rnk[k];
    }
    __syncthreads();
    for (int i = t; i < tot; i += BS) {
        int d = s_d[i];
        ev[d] = make_int2(s_o[i], s_v[i]);
        keyb[d] = s_k[i];
    }
}

// ---------------- build pass B: per-bucket counting sort (in-place via LDS) + row_ptr ----------------

__global__ void sort4(const int* y0, const int* y1, const int* y2, const int* y3,
                      int2* e0, int2* e1, int2* e2, int2* e3,
                      const int* __restrict__ bbase, const int* __restrict__ bcount,
                      int* rp0, int* rp1, int* rp2, int* rp3) {
    __shared__ int s_cnt[BS];
    __shared__ int s_cur[BS];
    __shared__ int2 s_ev[STAGE_B];
    int t = threadIdx.x;
    int p = blockIdx.x / NB;
    int b = blockIdx.x % NB;
    const int* keyb = (p == 0) ? y0 : (p == 1) ? y1 : (p == 2) ? y2 : y3;
    int2* ev = (p == 0) ? e0 : (p == 1) ? e1 : (p == 2) ? e2 : e3;
    int* rp  = (p == 0) ? rp0 : (p == 1) ? rp1 : (p == 2) ? rp2 : rp3;
    int SH = prob_sh(p);
    int n = prob_n(p);
    int base = bbase[p * NB_MAX + b];
    int cnt  = bcount[p * NB_MAX + b];
    int kb = b << SH;
    int span = min(1 << SH, n - kb);
    s_cnt[t] = 0;
    __syncthreads();
    for (int i = t; i < cnt; i += BS)
        atomicAdd(&s_cnt[keyb[base + i] - kb], 1);
    __syncthreads();
    int c = s_cnt[t];
    for (int off = 1; off < BS; off <<= 1) {
        int v = (t >= off) ? s_cnt[t - off] : 0;
        __syncthreads();
        s_cnt[t] += v;
        __syncthreads();
    }
    int lstart = s_cnt[t] - c;
    if (t < span) rp[kb + t] = base + lstart;
    if (b == NB - 1 && t == 0) rp[n] = NNZ;
    s_cur[t] = lstart;
    __syncthreads();
    for (int i = t; i < cnt; i += BS) {
        int r = atomicAdd(&s_cur[keyb[base + i] - kb], 1);
        s_ev[r] = ev[base + i];
    }
    __syncthreads();
    for (int i = t; i < cnt; i += BS) ev[base + i] = s_ev[i];
}

// ---------------- fp32 -> fp16 convert ----------------

__global__ void f32_to_h(const float* __restrict__ src, __half* __restrict__ dst, int n4) {
    int i = blockIdx.x * BS + threadIdx.x;
    if (i < n4) {
        float4 f = ((const float4*)src)[i];
        __half2* d = (__half2*)dst + (size_t)i * 2;
        d[0] = __floats2half2_rn(f.x, f.y);
        d[1] = __floats2half2_rn(f.z, f.w);
    }
}

// ---------------- SpMM: half-wave per row, fp16 gather, fp32 accum, 4-deep unroll ----------------

__global__ void spmm_h_kernel(const int* __restrict__ row_ptr, const int2* __restrict__ ev,
                              const __half2* __restrict__ x, __half2* __restrict__ y, int n_rows) {
    int row = blockIdx.x * 8 + (threadIdx.x >> 5);
    int l = threadIdx.x & 31;
    if (row >= n_rows) return;
    int p0 = row_ptr[row];
    int p1 = row_ptr[row + 1];
    float ax = 0.f, ay = 0.f;
    int j = p0;
    for (; j + 4 <= p1; j += 4) {
        int2 e0 = ev[j + 0];
        int2 e1 = ev[j + 1];
        int2 e2 = ev[j + 2];
        int2 e3 = ev[j + 3];
        __half2 h0 = x[(e0.x << 5) + l];
        __half2 h1 = x[(e1.x << 5) + l];
        __half2 h2 = x[(e2.x << 5) + l];
        __half2 h3 = x[(e3.x << 5) + l];
        float2 f0 = __half22float2(h0);
        float2 f1 = __half22float2(h1);
        float2 f2 = __half22float2(h2);
        float2 f3 = __half22float2(h3);
        float v0 = __int_as_float(e0.y);
        float v1 = __int_as_float(e1.y);
        float v2 = __int_as_float(e2.y);
        float v3 = __int_as_float(e3.y);
        ax = fmaf(v0, f0.x, ax); ay = fmaf(v0, f0.y, ay);
        ax = fmaf(v1, f1.x, ax); ay = fmaf(v1, f1.y, ay);
        ax = fmaf(v2, f2.x, ax); ay = fmaf(v2, f2.y, ay);
        ax = fmaf(v3, f3.x, ax); ay = fmaf(v3, f3.y, ay);
    }
    for (; j < p1; ++j) {
        int2 e = ev[j];
        float2 f = __half22float2(x[(e.x << 5) + l]);
        float v = __int_as_float(e.y);
        ax = fmaf(v, f.x, ax); ay = fmaf(v, f.y, ay);
    }
    y[(row << 5) + l] = __floats2half2_rn(ax, ay);
}

// ---------------- fused leaky_relu + LayerNorm + residual (fp16 h) ----------------

__global__ void fused_ln_h(const __half* h, const float* __restrict__ embs,
                           const float* __restrict__ gamma, const float* __restrict__ beta,
                           __half* xh_out, float* f_out, int apply_leaky) {
    int row = blockIdx.x * 4 + (threadIdx.x >> 6);
    int lane = threadIdx.x & 63;
    if (row >= N_NODES) return;
    float v = __half2float(h[(row << 6) + lane]);
    if (apply_leaky) v = (v > 0.f) ? v : 0.2f * v;
    float s = v;
    for (int off = 32; off > 0; off >>= 1) s += __shfl_xor(s, off, 64);
    float mu = s * (1.0f / D);
    float dd = v - mu;
    float q = dd * dd;
    for (int off = 32; off > 0; off >>= 1) q += __shfl_xor(q, off, 64);
    float var = q * (1.0f / D);
    float res = dd * rsqrtf(var + 1e-5f) * gamma[lane] + beta[lane] + embs[(row << 6) + lane];
    if (xh_out) xh_out[(row << 6) + lane] = __float2half(res);
    else f_out[(row << 6) + lane] = res;
}

// ---------------- fallback: COO atomic SpMM + fp32 LN (used only if ws too small) ----------------

__global__ void spmm_atomic_kernel(const int* __restrict__ keys, const int* __restrict__ other,
                                   const float* __restrict__ vals, const float* __restrict__ x,
                                   float* __restrict__ y) {
    long i = (long)blockIdx.x * 256 + threadIdx.x;
    int e = (int)(i >> 4);
    int sub = ((int)i & 15) * 4;
    if (e >= NNZ) return;
    int r = keys[e];
    int c = other[e];
    float v = vals[e];
    const float4 xv = *(const float4*)&x[c * D + sub];
    atomicAdd(&y[r * D + sub + 0], v * xv.x);
    atomicAdd(&y[r * D + sub + 1], v * xv.y);
    atomicAdd(&y[r * D + sub + 2], v * xv.z);
    atomicAdd(&y[r * D + sub + 3], v * xv.w);
}

__global__ void fused_ln_kernel(float* __restrict__ h, const float* __restrict__ embs,
                                const float* __restrict__ gamma, const float* __restrict__ beta,
                                int n_rows, int apply_leaky) {
    int row = blockIdx.x * 4 + (threadIdx.x >> 6);
    int lane = threadIdx.x & 63;
    if (row >= n_rows) return;
    float v = h[row * D + lane];
    if (apply_leaky) v = (v > 0.f) ? v : 0.2f * v;
    float s = v;
    for (int off = 32; off > 0; off >>= 1) s += __shfl_xor(s, off, 64);
    float mu = s * (1.0f / D);
    float dd = v - mu;
    float q = dd * dd;
    for (int off = 32; off > 0; off >>= 1) q += __shfl_xor(q, off, 64);
    float var = q * (1.0f / D);
    h[row * D + lane] = dd * rsqrtf(var + 1e-5f) * gamma[lane] + beta[lane]
                        + embs[row * D + lane];
}

extern "C" void kernel_launch(void* const* d_in, const int* in_sizes, int n_in,
                              void* d_out, int out_size, void* d_ws, size_t ws_size,
                              hipStream_t stream) {
    const float* embs   = (const float*)d_in[0];
    const int*   A_rows = (const int*)d_in[1];
    const int*   A_cols = (const int*)d_in[2];
    const float* A_vals = (const float*)d_in[3];
    const int*   S_rows = (const int*)d_in[4];
    const int*   S_cols = (const int*)d_in[5];
    const float* S_vals = (const float*)d_in[6];
    const float* gamma  = (const float*)d_in[7];   // [2][64]
    const float* beta   = (const float*)d_in[8];   // [2][64]
    float* out = (float*)d_out;

    // ---- workspace layout ----
    size_t off = 0;
    auto bump = [&](size_t b) { size_t o = off; off += (b + 255) & ~(size_t)255; return o; };
    size_t o_xh   = bump((size_t)N_NODES * D * 2);   // x fp16; also h (t4) — aliases safely
    size_t o_th   = bump((size_t)N_NODES * D * 2);   // t1/t3 fp16; build-phase: keyb[0..3] (32MB)
    size_t o_tHh  = bump((size_t)H_EDGES * D * 2);   // t2 fp16 (contiguous after th)
    size_t o_ev[4];
    for (int i = 0; i < 4; ++i) o_ev[i] = bump((size_t)NNZ * 8);
    size_t o_rpAT = bump((size_t)(N_NODES + 1) * 4);
    size_t o_rpST = bump((size_t)(H_EDGES + 1) * 4);
    size_t o_rpS  = bump((size_t)(N_NODES + 1) * 4);
    size_t o_rpA  = bump((size_t)(N_NODES + 1) * 4);
    size_t o_bcount = bump((size_t)4 * NB_MAX * 4);
    size_t o_bbase  = bump((size_t)4 * NB_MAX * 4);
    size_t o_gcur   = bump((size_t)4 * NB_MAX * 4);
    size_t needed_csr = off;

    char* w = (char*)d_ws;
    __half* xh  = (__half*)(w + o_xh);
    __half* th  = (__half*)(w + o_th);
    __half* tHh = (__half*)(w + o_tHh);
    __half* hh  = xh;                               // h aliases x (safe by schedule)
    int2* evb[4];
    for (int i = 0; i < 4; ++i) evb[i] = (int2*)(w + o_ev[i]);
    int* keyb[4];
    for (int i = 0; i < 4; ++i) keyb[i] = (int*)(w + o_th + (size_t)i * NNZ * 4);
    int* rpAT = (int*)(w + o_rpAT);
    int* rpST = (int*)(w + o_rpST);
    int* rpS  = (int*)(w + o_rpS);
    int* rpA  = (int*)(w + o_rpA);
    int* bcount = (int*)(w + o_bcount);
    int* bbase  = (int*)(w + o_bbase);
    int* gcur   = (int*)(w + o_gcur);

    bool use_csr = (ws_size >= needed_csr);

    if (use_csr) {
        // ---- unified build (4 sorts, 5 launches) ----
        hipMemsetAsync(bcount, 0, (size_t)4 * NB_MAX * 4, stream);
        hist4<<<4 * NBLK, BS, 0, stream>>>(A_cols, S_cols, S_rows, A_rows, bcount);
        spine4<<<4, BS, 0, stream>>>(bcount, bbase, gcur);
        scatter4<<<4 * NBLK, BS, 0, stream>>>(A_cols, A_rows, A_vals,
                                              S_cols, S_rows, S_vals,
                                              S_rows, S_cols, S_vals,
                                              A_rows, A_cols, A_vals,
                                              gcur,
                                              evb[0], evb[1], evb[2], evb[3],
                                              keyb[0], keyb[1], keyb[2], keyb[3]);
        sort4<<<4 * NB, BS, 0, stream>>>(keyb[0], keyb[1], keyb[2], keyb[3],
                                         evb[0], evb[1], evb[2], evb[3],
                                         bbase, bcount, rpAT, rpST, rpS, rpA);

        // ---- embs -> fp16 ----
        int n4 = N_NODES * D / 4;
        f32_to_h<<<(n4 + BS - 1) / BS, BS, 0, stream>>>(embs, xh, n4);

        auto spmm = [&](int* rp, int2* ev, const __half* x, __half* y, int n) {
            spmm_h_kernel<<<(n + 7) / 8, BS, 0, stream>>>(rp, ev, (const __half2*)x,
                                                          (__half2*)y, n);
        };

        for (int layer = 0; layer < 2; ++layer) {
            spmm(rpAT, evb[0], xh,  th,  N_NODES);   // t1 = A^T x   [N]  (xh dead after)
            spmm(rpST, evb[1], th,  tHh, H_EDGES);   // t2 = S^T t1  [H]
            spmm(rpS,  evb[2], tHh, th,  N_NODES);   // t3 = S t2    [N]
            spmm(rpA,  evb[3], th,  hh,  N_NODES);   // t4 = A t3    [N]  (hh == xh)
            if (layer == 0)
                fused_ln_h<<<(N_NODES + 3) / 4, BS, 0, stream>>>(
                    hh, embs, gamma, beta, xh, nullptr, 1);
            else
                fused_ln_h<<<(N_NODES + 3) / 4, BS, 0, stream>>>(
                    hh, embs, gamma + D, beta + D, nullptr, out, 0);
        }
    } else {
        // COO + atomics fallback (needs only 64 MB)
        float* B1 = (float*)w;
        float* BH = (float*)(w + (size_t)N_NODES * D * 4);
        auto spmm_at = [&](const int* keys, const int* other, const float* vals,
                           const float* x, float* y, int n) {
            hipMemsetAsync(y, 0, (size_t)n * D * 4, stream);
            long threads = (long)NNZ * 16;
            int blocks = (int)((threads + 255) / 256);
            spmm_atomic_kernel<<<blocks, 256, 0, stream>>>(keys, other, vals, x, y);
        };
        for (int layer = 0; layer < 2; ++layer) {
            const float* xin = (layer == 0) ? embs : out;
            spmm_at(A_cols, A_rows, A_vals, xin, B1, N_NODES);
            spmm_at(S_cols, S_rows, S_vals, B1,  BH, H_EDGES);
            spmm_at(S_rows, S_cols, S_vals, BH,  B1, N_NODES);
            spmm_at(A_rows, A_cols, A_vals, B1,  out, N_NODES);
            fused_ln_kernel<<<(N_NODES + 3) / 4, 256, 0, stream>>>(
                out, embs, gamma + layer * D, beta + layer * D, N_NODES, layer == 0 ? 1 : 0);
        }
    }
}

// Round 5
// 636.645 us; speedup vs baseline: 3.8199x; 1.2721x over previous
//
#include <hip/hip_runtime.h>
#include <hip/hip_fp16.h>

#define N_NODES 200000
#define H_EDGES 50000
#define D 64
#define NNZ 2000000

#define BS 256
#define EPB 12
#define EDGES_PER_BLOCK (EPB * BS)                            // 3072
#define NBLK ((NNZ + EDGES_PER_BLOCK - 1) / EDGES_PER_BLOCK)  // 652
#define NB 391        // ceil(200000/512) == ceil(50000/128) == 391
#define NB_MAX 392
#define SPAN_N 512
#define STAGE_B 6144
#define OTHER_MASK 0x3FFFF

// problem p: 0 = A^T (keys A_cols, SH=9), 1 = S^T (keys S_cols, SH=7), 2 = S (S_rows), 3 = A (A_rows)
__device__ __forceinline__ int prob_sh(int p) { return (p == 1) ? 7 : 9; }
__device__ __forceinline__ int prob_n(int p)  { return (p == 1) ? H_EDGES : N_NODES; }

// ---------------- build pass 0: per-bucket histogram (4 problems, one grid) ----------------

__global__ void hist4(const int* __restrict__ k0, const int* __restrict__ k1,
                      const int* __restrict__ k2, const int* __restrict__ k3,
                      int* __restrict__ bcount) {
    __shared__ int sh_[NB_MAX];
    int t = threadIdx.x;
    int p = blockIdx.x / NBLK;
    int lb = blockIdx.x % NBLK;
    const int* keys = (p == 0) ? k0 : (p == 1) ? k1 : (p == 2) ? k2 : k3;
    int SH = prob_sh(p);
    for (int i = t; i < NB; i += BS) sh_[i] = 0;
    __syncthreads();
    int base = lb * EDGES_PER_BLOCK;
#pragma unroll
    for (int k = 0; k < EPB; ++k) {
        int e = base + k * BS + t;
        if (e < NNZ) atomicAdd(&sh_[keys[e] >> SH], 1);
    }
    __syncthreads();
    int* bc = bcount + p * NB_MAX;
    for (int i = t; i < NB; i += BS) if (sh_[i]) atomicAdd(&bc[i], sh_[i]);
}

// ---------------- build spine: per-problem exclusive scan (2 elems/thread) ----------------

__global__ void spine4(const int* __restrict__ bcount, int* __restrict__ bbase,
                       int* __restrict__ gcur) {
    __shared__ int tmp[BS];
    int p = blockIdx.x, t = threadIdx.x;
    const int* bc = bcount + p * NB_MAX;
    int i0 = 2 * t, i1 = 2 * t + 1;
    int c0 = (i0 < NB) ? bc[i0] : 0;
    int c1 = (i1 < NB) ? bc[i1] : 0;
    int s = c0 + c1;
    tmp[t] = s;
    __syncthreads();
    for (int off = 1; off < BS; off <<= 1) {
        int v = (t >= off) ? tmp[t - off] : 0;
        __syncthreads();
        tmp[t] += v;
        __syncthreads();
    }
    int base = tmp[t] - s;
    if (i0 < NB) { bbase[p * NB_MAX + i0] = base; gcur[p * NB_MAX + i0] = base; base += c0; }
    if (i1 < NB) { bbase[p * NB_MAX + i1] = base; gcur[p * NB_MAX + i1] = base; }
}

// ---------------- build pass A: LDS-staged bucket scatter -> packed int2 ----------------
// packed entry: .x = other | (key_in_bucket << 18), .y = val bits

__global__ void scatter4(const int* k0, const int* o0, const float* v0_,
                         const int* k1, const int* o1, const float* v1_,
                         const int* k2, const int* o2, const float* v2_,
                         const int* k3, const int* o3, const float* v3_,
                         int* __restrict__ gcur,
                         int2* e0, int2* e1, int2* e2, int2* e3) {
    __shared__ int s_hist[NB_MAX];
    __shared__ int s_garr[NB_MAX];
    __shared__ int s_tmp[BS];
    __shared__ int2 s_ev[EDGES_PER_BLOCK];
    __shared__ int s_d[EDGES_PER_BLOCK];
    int t = threadIdx.x;
    int p = blockIdx.x / NBLK;
    int lb = blockIdx.x % NBLK;
    const int*   keys  = (p == 0) ? k0 : (p == 1) ? k1 : (p == 2) ? k2 : k3;
    const int*   other = (p == 0) ? o0 : (p == 1) ? o1 : (p == 2) ? o2 : o3;
    const float* vals  = (p == 0) ? v0_ : (p == 1) ? v1_ : (p == 2) ? v2_ : v3_;
    int2* ev_out = (p == 0) ? e0 : (p == 1) ? e1 : (p == 2) ? e2 : e3;
    int SH = prob_sh(p);
    int KM = (1 << SH) - 1;
    int* gc = gcur + p * NB_MAX;

    int blkbase = lb * EDGES_PER_BLOCK;
    int tot = min(EDGES_PER_BLOCK, NNZ - blkbase);
    for (int i = t; i < NB; i += BS) s_hist[i] = 0;
    __syncthreads();
    int bkt[EPB], meta[EPB];   // meta = rank | (klo<<13)
#pragma unroll
    for (int k = 0; k < EPB; ++k) {
        int e = blkbase + k * BS + t;
        if (e < NNZ) {
            int key = keys[e];
            int b = key >> SH;
            bkt[k] = b;
            meta[k] = atomicAdd(&s_hist[b], 1) | ((key & KM) << 13);
        } else bkt[k] = -1;
    }
    __syncthreads();
    // exclusive scan of s_hist -> local starts; reserve global ranges (2 elems/thread)
    int i0 = 2 * t, i1 = 2 * t + 1;
    int c0 = (i0 < NB) ? s_hist[i0] : 0;
    int c1 = (i1 < NB) ? s_hist[i1] : 0;
    int ssum = c0 + c1;
    s_tmp[t] = ssum;
    __syncthreads();
    for (int off = 1; off < BS; off <<= 1) {
        int v = (t >= off) ? s_tmp[t - off] : 0;
        __syncthreads();
        s_tmp[t] += v;
        __syncthreads();
    }
    int ebase = s_tmp[t] - ssum;
    if (i0 < NB) {
        s_hist[i0] = ebase;
        if (c0 > 0) s_garr[i0] = atomicAdd(&gc[i0], c0);
        ebase += c0;
    }
    if (i1 < NB) {
        s_hist[i1] = ebase;
        if (c1 > 0) s_garr[i1] = atomicAdd(&gc[i1], c1);
    }
    __syncthreads();
    // stage packed edges grouped by bucket
#pragma unroll
    for (int k = 0; k < EPB; ++k) {
        if (bkt[k] < 0) continue;
        int e = blkbase + k * BS + t;
        int rnk = meta[k] & 0x1FFF;
        int klo = meta[k] >> 13;
        int pos = s_hist[bkt[k]] + rnk;
        s_ev[pos] = make_int2(other[e] | (klo << 18), __float_as_int(vals[e]));
        s_d[pos] = s_garr[bkt[k]] + rnk;
    }
    __syncthreads();
    for (int i = t; i < tot; i += BS)
        ev_out[s_d[i]] = s_ev[i];
}

// ---------------- build pass B: per-bucket counting sort (in-place via LDS) + row_ptr ----------------

__global__ void sort4(int2* e0, int2* e1, int2* e2, int2* e3,
                      const int* __restrict__ bbase, const int* __restrict__ bcount,
                      int* rp0, int* rp1, int* rp2, int* rp3) {
    __shared__ int s_cnt[SPAN_N];
    __shared__ int s_tmp[BS];
    __shared__ int2 s_ev[STAGE_B];
    int t = threadIdx.x;
    int p = blockIdx.x / NB;
    int b = blockIdx.x % NB;
    int2* ev = (p == 0) ? e0 : (p == 1) ? e1 : (p == 2) ? e2 : e3;
    int* rp  = (p == 0) ? rp0 : (p == 1) ? rp1 : (p == 2) ? rp2 : rp3;
    int SH = prob_sh(p);
    int n = prob_n(p);
    int base = bbase[p * NB_MAX + b];
    int cnt  = bcount[p * NB_MAX + b];
    int kb = b << SH;
    int span = min(1 << SH, n - kb);
    for (int k = t; k < span; k += BS) s_cnt[k] = 0;
    __syncthreads();
    for (int i = t; i < cnt; i += BS)
        atomicAdd(&s_cnt[ev[base + i].x >> 18], 1);
    __syncthreads();
    // scan span (<=512): 2 elems/thread -> exclusive starts back into s_cnt
    int i0 = 2 * t, i1 = 2 * t + 1;
    int c0 = (i0 < span) ? s_cnt[i0] : 0;
    int c1 = (i1 < span) ? s_cnt[i1] : 0;
    int s = c0 + c1;
    s_tmp[t] = s;
    __syncthreads();
    for (int off = 1; off < BS; off <<= 1) {
        int v = (t >= off) ? s_tmp[t - off] : 0;
        __syncthreads();
        s_tmp[t] += v;
        __syncthreads();
    }
    int ex = s_tmp[t] - s;
    __syncthreads();
    if (i0 < span) { rp[kb + i0] = base + ex; s_cnt[i0] = ex; ex += c0; }
    if (i1 < span) { rp[kb + i1] = base + ex; s_cnt[i1] = ex; }
    if (b == NB - 1 && t == 0) rp[n] = NNZ;
    __syncthreads();
    for (int i = t; i < cnt; i += BS) {
        int2 e = ev[base + i];
        int r = atomicAdd(&s_cnt[e.x >> 18], 1);
        if (r < STAGE_B) s_ev[r] = make_int2(e.x & OTHER_MASK, e.y);
    }
    __syncthreads();
    int lim = min(cnt, STAGE_B);
    for (int i = t; i < lim; i += BS) ev[base + i] = s_ev[i];
}

// ---------------- fp32 -> fp16 convert ----------------

__global__ void f32_to_h(const float* __restrict__ src, __half* __restrict__ dst, int n4) {
    int i = blockIdx.x * BS + threadIdx.x;
    if (i < n4) {
        float4 f = ((const float4*)src)[i];
        __half2* d = (__half2*)dst + (size_t)i * 2;
        d[0] = __floats2half2_rn(f.x, f.y);
        d[1] = __floats2half2_rn(f.z, f.w);
    }
}

// ---------------- SpMM: quarter-wave (16 lanes, uint2) per row, fp32 accum, 4-deep unroll ----------------

__global__ void spmm_h_kernel(const int* __restrict__ row_ptr, const int2* __restrict__ ev,
                              const uint2* __restrict__ x, uint2* __restrict__ y, int n_rows) {
    int row = blockIdx.x * 16 + (threadIdx.x >> 4);
    int l = threadIdx.x & 15;
    if (row >= n_rows) return;
    int p0 = row_ptr[row];
    int p1 = row_ptr[row + 1];
    float a0 = 0.f, a1 = 0.f, a2 = 0.f, a3 = 0.f;
    int j = p0;
#define ACC(g, v) {                                                   \
        __half2 hA = *(__half2*)&(g).x;                               \
        __half2 hB = *(__half2*)&(g).y;                               \
        float2 fA = __half22float2(hA);                               \
        float2 fB = __half22float2(hB);                               \
        a0 = fmaf((v), fA.x, a0); a1 = fmaf((v), fA.y, a1);           \
        a2 = fmaf((v), fB.x, a2); a3 = fmaf((v), fB.y, a3);           \
    }
    for (; j + 4 <= p1; j += 4) {
        int2 e0 = ev[j + 0];
        int2 e1 = ev[j + 1];
        int2 e2 = ev[j + 2];
        int2 e3 = ev[j + 3];
        uint2 g0 = x[(e0.x << 4) + l];
        uint2 g1 = x[(e1.x << 4) + l];
        uint2 g2 = x[(e2.x << 4) + l];
        uint2 g3 = x[(e3.x << 4) + l];
        float v0 = __int_as_float(e0.y);
        float v1 = __int_as_float(e1.y);
        float v2 = __int_as_float(e2.y);
        float v3 = __int_as_float(e3.y);
        ACC(g0, v0); ACC(g1, v1); ACC(g2, v2); ACC(g3, v3);
    }
    for (; j < p1; ++j) {
        int2 e = ev[j];
        uint2 g = x[(e.x << 4) + l];
        float v = __int_as_float(e.y);
        ACC(g, v);
    }
#undef ACC
    uint2 o;
    __half2 oA = __floats2half2_rn(a0, a1);
    __half2 oB = __floats2half2_rn(a2, a3);
    o.x = *(unsigned int*)&oA;
    o.y = *(unsigned int*)&oB;
    y[(row << 4) + l] = o;
}

// ---------------- fused leaky_relu + LayerNorm + residual (fp16 h) ----------------

__global__ void fused_ln_h(const __half* h, const float* __restrict__ embs,
                           const float* __restrict__ gamma, const float* __restrict__ beta,
                           __half* xh_out, float* f_out, int apply_leaky) {
    int row = blockIdx.x * 4 + (threadIdx.x >> 6);
    int lane = threadIdx.x & 63;
    if (row >= N_NODES) return;
    float v = __half2float(h[(row << 6) + lane]);
    if (apply_leaky) v = (v > 0.f) ? v : 0.2f * v;
    float s = v;
    for (int off = 32; off > 0; off >>= 1) s += __shfl_xor(s, off, 64);
    float mu = s * (1.0f / D);
    float dd = v - mu;
    float q = dd * dd;
    for (int off = 32; off > 0; off >>= 1) q += __shfl_xor(q, off, 64);
    float var = q * (1.0f / D);
    float res = dd * rsqrtf(var + 1e-5f) * gamma[lane] + beta[lane] + embs[(row << 6) + lane];
    if (xh_out) xh_out[(row << 6) + lane] = __float2half(res);
    else f_out[(row << 6) + lane] = res;
}

// ---------------- fallback: COO atomic SpMM + fp32 LN (used only if ws too small) ----------------

__global__ void spmm_atomic_kernel(const int* __restrict__ keys, const int* __restrict__ other,
                                   const float* __restrict__ vals, const float* __restrict__ x,
                                   float* __restrict__ y) {
    long i = (long)blockIdx.x * 256 + threadIdx.x;
    int e = (int)(i >> 4);
    int sub = ((int)i & 15) * 4;
    if (e >= NNZ) return;
    int r = keys[e];
    int c = other[e];
    float v = vals[e];
    const float4 xv = *(const float4*)&x[c * D + sub];
    atomicAdd(&y[r * D + sub + 0], v * xv.x);
    atomicAdd(&y[r * D + sub + 1], v * xv.y);
    atomicAdd(&y[r * D + sub + 2], v * xv.z);
    atomicAdd(&y[r * D + sub + 3], v * xv.w);
}

__global__ void fused_ln_kernel(float* __restrict__ h, const float* __restrict__ embs,
                                const float* __restrict__ gamma, const float* __restrict__ beta,
                                int n_rows, int apply_leaky) {
    int row = blockIdx.x * 4 + (threadIdx.x >> 6);
    int lane = threadIdx.x & 63;
    if (row >= n_rows) return;
    float v = h[row * D + lane];
    if (apply_leaky) v = (v > 0.f) ? v : 0.2f * v;
    float s = v;
    for (int off = 32; off > 0; off >>= 1) s += __shfl_xor(s, off, 64);
    float mu = s * (1.0f / D);
    float dd = v - mu;
    float q = dd * dd;
    for (int off = 32; off > 0; off >>= 1) q += __shfl_xor(q, off, 64);
    float var = q * (1.0f / D);
    h[row * D + lane] = dd * rsqrtf(var + 1e-5f) * gamma[lane] + beta[lane]
                        + embs[row * D + lane];
}

extern "C" void kernel_launch(void* const* d_in, const int* in_sizes, int n_in,
                              void* d_out, int out_size, void* d_ws, size_t ws_size,
                              hipStream_t stream) {
    const float* embs   = (const float*)d_in[0];
    const int*   A_rows = (const int*)d_in[1];
    const int*   A_cols = (const int*)d_in[2];
    const float* A_vals = (const float*)d_in[3];
    const int*   S_rows = (const int*)d_in[4];
    const int*   S_cols = (const int*)d_in[5];
    const float* S_vals = (const float*)d_in[6];
    const float* gamma  = (const float*)d_in[7];   // [2][64]
    const float* beta   = (const float*)d_in[8];   // [2][64]
    float* out = (float*)d_out;

    // ---- workspace layout ----
    size_t off = 0;
    auto bump = [&](size_t b) { size_t o = off; off += (b + 255) & ~(size_t)255; return o; };
    size_t o_xh   = bump((size_t)N_NODES * D * 2);   // x fp16; also h (t4)
    size_t o_th   = bump((size_t)N_NODES * D * 2);   // t1/t3 fp16
    size_t o_tHh  = bump((size_t)H_EDGES * D * 2);   // t2 fp16
    size_t o_ev[4];
    for (int i = 0; i < 4; ++i) o_ev[i] = bump((size_t)NNZ * 8);
    size_t o_rpAT = bump((size_t)(N_NODES + 1) * 4);
    size_t o_rpST = bump((size_t)(H_EDGES + 1) * 4);
    size_t o_rpS  = bump((size_t)(N_NODES + 1) * 4);
    size_t o_rpA  = bump((size_t)(N_NODES + 1) * 4);
    size_t o_bcount = bump((size_t)4 * NB_MAX * 4);
    size_t o_bbase  = bump((size_t)4 * NB_MAX * 4);
    size_t o_gcur   = bump((size_t)4 * NB_MAX * 4);
    size_t needed_csr = off;

    char* w = (char*)d_ws;
    __half* xh  = (__half*)(w + o_xh);
    __half* th  = (__half*)(w + o_th);
    __half* tHh = (__half*)(w + o_tHh);
    __half* hh  = xh;                               // h aliases x (safe by schedule)
    int2* evb[4];
    for (int i = 0; i < 4; ++i) evb[i] = (int2*)(w + o_ev[i]);
    int* rpAT = (int*)(w + o_rpAT);
    int* rpST = (int*)(w + o_rpST);
    int* rpS  = (int*)(w + o_rpS);
    int* rpA  = (int*)(w + o_rpA);
    int* bcount = (int*)(w + o_bcount);
    int* bbase  = (int*)(w + o_bbase);
    int* gcur   = (int*)(w + o_gcur);

    bool use_csr = (ws_size >= needed_csr);

    if (use_csr) {
        // ---- unified build (4 sorts, 5 launches) ----
        hipMemsetAsync(bcount, 0, (size_t)4 * NB_MAX * 4, stream);
        hist4<<<4 * NBLK, BS, 0, stream>>>(A_cols, S_cols, S_rows, A_rows, bcount);
        spine4<<<4, BS, 0, stream>>>(bcount, bbase, gcur);
        scatter4<<<4 * NBLK, BS, 0, stream>>>(A_cols, A_rows, A_vals,
                                              S_cols, S_rows, S_vals,
                                              S_rows, S_cols, S_vals,
                                              A_rows, A_cols, A_vals,
                                              gcur,
                                              evb[0], evb[1], evb[2], evb[3]);
        sort4<<<4 * NB, BS, 0, stream>>>(evb[0], evb[1], evb[2], evb[3],
                                         bbase, bcount, rpAT, rpST, rpS, rpA);

        // ---- embs -> fp16 ----
        int n4 = N_NODES * D / 4;
        f32_to_h<<<(n4 + BS - 1) / BS, BS, 0, stream>>>(embs, xh, n4);

        auto spmm = [&](int* rp, int2* ev, const __half* x, __half* y, int n) {
            spmm_h_kernel<<<(n + 15) / 16, BS, 0, stream>>>(rp, ev, (const uint2*)x,
                                                            (uint2*)y, n);
        };

        for (int layer = 0; layer < 2; ++layer) {
            spmm(rpAT, evb[0], xh,  th,  N_NODES);   // t1 = A^T x   [N]  (xh dead after)
            spmm(rpST, evb[1], th,  tHh, H_EDGES);   // t2 = S^T t1  [H]
            spmm(rpS,  evb[2], tHh, th,  N_NODES);   // t3 = S t2    [N]
            spmm(rpA,  evb[3], th,  hh,  N_NODES);   // t4 = A t3    [N]  (hh == xh)
            if (layer == 0)
                fused_ln_h<<<(N_NODES + 3) / 4, BS, 0, stream>>>(
                    hh, embs, gamma, beta, xh, nullptr, 1);
            else
                fused_ln_h<<<(N_NODES + 3) / 4, BS, 0, stream>>>(
                    hh, embs, gamma + D, beta + D, nullptr, out, 0);
        }
    } else {
        // COO + atomics fallback (needs only 64 MB)
        float* B1 = (float*)w;
        float* BH = (float*)(w + (size_t)N_NODES * D * 4);
        auto spmm_at = [&](const int* keys, const int* other, const float* vals,
                           const float* x, float* y, int n) {
            hipMemsetAsync(y, 0, (size_t)n * D * 4, stream);
            long threads = (long)NNZ * 16;
            int blocks = (int)((threads + 255) / 256);
            spmm_atomic_kernel<<<blocks, 256, 0, stream>>>(keys, other, vals, x, y);
        };
        for (int layer = 0; layer < 2; ++layer) {
            const float* xin = (layer == 0) ? embs : out;
            spmm_at(A_cols, A_rows, A_vals, xin, B1, N_NODES);
            spmm_at(S_cols, S_rows, S_vals, B1,  BH, H_EDGES);
            spmm_at(S_rows, S_cols, S_vals, BH,  B1, N_NODES);
            spmm_at(A_rows, A_cols, A_vals, B1,  out, N_NODES);
            fused_ln_kernel<<<(N_NODES + 3) / 4, 256, 0, stream>>>(
                out, embs, gamma + layer * D, beta + layer * D, N_NODES, layer == 0 ? 1 : 0);
        }
    }
}

// Round 6
// 610.074 us; speedup vs baseline: 3.9863x; 1.0436x over previous
//
#include <hip/hip_runtime.h>
#include <hip/hip_fp16.h>

#define N_NODES 200000
#define H_EDGES 50000
#define D 64
#define NNZ 2000000

#define BS 256
#define EPB 12
#define EDGES_PER_BLOCK (EPB * BS)                            // 3072
#define NBLK ((NNZ + EDGES_PER_BLOCK - 1) / EDGES_PER_BLOCK)  // 652
#define NB 391        // ceil(200000/512) == ceil(50000/128) == 391
#define NB_MAX 392
#define SPAN_N 512
#define STAGE_B 6144
#define OTHER_MASK 0x3FFFF

// problem p: 0 = A^T (keys A_cols, SH=9), 1 = S^T (keys S_cols, SH=7), 2 = S (S_rows), 3 = A (A_rows)
__device__ __forceinline__ int prob_sh(int p) { return (p == 1) ? 7 : 9; }
__device__ __forceinline__ int prob_n(int p)  { return (p == 1) ? H_EDGES : N_NODES; }

// ---------------- build pass 0: per-bucket histogram (4 problems, one grid) ----------------

__global__ void hist4(const int* __restrict__ k0, const int* __restrict__ k1,
                      const int* __restrict__ k2, const int* __restrict__ k3,
                      int* __restrict__ bcount) {
    __shared__ int sh_[NB_MAX];
    int t = threadIdx.x;
    int p = blockIdx.x / NBLK;
    int lb = blockIdx.x % NBLK;
    const int* keys = (p == 0) ? k0 : (p == 1) ? k1 : (p == 2) ? k2 : k3;
    int SH = prob_sh(p);
    for (int i = t; i < NB; i += BS) sh_[i] = 0;
    __syncthreads();
    int base = lb * EDGES_PER_BLOCK;
#pragma unroll
    for (int k = 0; k < EPB; ++k) {
        int e = base + k * BS + t;
        if (e < NNZ) atomicAdd(&sh_[keys[e] >> SH], 1);
    }
    __syncthreads();
    int* bc = bcount + p * NB_MAX;
    for (int i = t; i < NB; i += BS) if (sh_[i]) atomicAdd(&bc[i], sh_[i]);
}

// ---------------- build spine: per-problem exclusive scan (2 elems/thread) ----------------

__global__ void spine4(const int* __restrict__ bcount, int* __restrict__ bbase,
                       int* __restrict__ gcur) {
    __shared__ int tmp[BS];
    int p = blockIdx.x, t = threadIdx.x;
    const int* bc = bcount + p * NB_MAX;
    int i0 = 2 * t, i1 = 2 * t + 1;
    int c0 = (i0 < NB) ? bc[i0] : 0;
    int c1 = (i1 < NB) ? bc[i1] : 0;
    int s = c0 + c1;
    tmp[t] = s;
    __syncthreads();
    for (int off = 1; off < BS; off <<= 1) {
        int v = (t >= off) ? tmp[t - off] : 0;
        __syncthreads();
        tmp[t] += v;
        __syncthreads();
    }
    int base = tmp[t] - s;
    if (i0 < NB) { bbase[p * NB_MAX + i0] = base; gcur[p * NB_MAX + i0] = base; base += c0; }
    if (i1 < NB) { bbase[p * NB_MAX + i1] = base; gcur[p * NB_MAX + i1] = base; }
}

// ---------------- build pass A: LDS-staged bucket scatter -> packed int2 ----------------
// packed entry: .x = other | (key_in_bucket << 18), .y = val bits

__global__ __launch_bounds__(BS, 4)
void scatter4(const int* k0, const int* o0, const float* v0_,
              const int* k1, const int* o1, const float* v1_,
              const int* k2, const int* o2, const float* v2_,
              const int* k3, const int* o3, const float* v3_,
              int* __restrict__ gcur,
              int2* e0, int2* e1, int2* e2, int2* e3) {
    __shared__ int s_hist[NB_MAX];
    __shared__ int s_garr[NB_MAX];
    __shared__ int s_tmp[BS];
    __shared__ int2 s_ev[EDGES_PER_BLOCK];
    __shared__ unsigned short s_bkt[EDGES_PER_BLOCK];
    int t = threadIdx.x;
    int p = blockIdx.x / NBLK;
    int lb = blockIdx.x % NBLK;
    const int*   keys  = (p == 0) ? k0 : (p == 1) ? k1 : (p == 2) ? k2 : k3;
    const int*   other = (p == 0) ? o0 : (p == 1) ? o1 : (p == 2) ? o2 : o3;
    const float* vals  = (p == 0) ? v0_ : (p == 1) ? v1_ : (p == 2) ? v2_ : v3_;
    int2* ev_out = (p == 0) ? e0 : (p == 1) ? e1 : (p == 2) ? e2 : e3;
    int SH = prob_sh(p);
    int KM = (1 << SH) - 1;
    int* gc = gcur + p * NB_MAX;

    int blkbase = lb * EDGES_PER_BLOCK;
    int tot = min(EDGES_PER_BLOCK, NNZ - blkbase);
    for (int i = t; i < NB; i += BS) s_hist[i] = 0;
    __syncthreads();
    int bkt[EPB], meta[EPB];   // meta = rank | (klo<<13)
#pragma unroll
    for (int k = 0; k < EPB; ++k) {
        int e = blkbase + k * BS + t;
        if (e < NNZ) {
            int key = keys[e];
            int b = key >> SH;
            bkt[k] = b;
            meta[k] = atomicAdd(&s_hist[b], 1) | ((key & KM) << 13);
        } else bkt[k] = -1;
    }
    __syncthreads();
    // exclusive scan of s_hist -> local starts; reserve global ranges (2 elems/thread)
    int i0 = 2 * t, i1 = 2 * t + 1;
    int c0 = (i0 < NB) ? s_hist[i0] : 0;
    int c1 = (i1 < NB) ? s_hist[i1] : 0;
    int ssum = c0 + c1;
    s_tmp[t] = ssum;
    __syncthreads();
    for (int off = 1; off < BS; off <<= 1) {
        int v = (t >= off) ? s_tmp[t - off] : 0;
        __syncthreads();
        s_tmp[t] += v;
        __syncthreads();
    }
    int ebase = s_tmp[t] - ssum;
    if (i0 < NB) {
        s_hist[i0] = ebase;
        if (c0 > 0) s_garr[i0] = atomicAdd(&gc[i0], c0);
        ebase += c0;
    }
    if (i1 < NB) {
        s_hist[i1] = ebase;
        if (c1 > 0) s_garr[i1] = atomicAdd(&gc[i1], c1);
    }
    __syncthreads();
    // stage packed edges grouped by bucket
#pragma unroll
    for (int k = 0; k < EPB; ++k) {
        if (bkt[k] < 0) continue;
        int e = blkbase + k * BS + t;
        int rnk = meta[k] & 0x1FFF;
        int klo = meta[k] >> 13;
        int pos = s_hist[bkt[k]] + rnk;
        s_ev[pos] = make_int2(other[e] | (klo << 18), __float_as_int(vals[e]));
        s_bkt[pos] = (unsigned short)bkt[k];
    }
    __syncthreads();
    for (int i = t; i < tot; i += BS) {
        int b = s_bkt[i];
        ev_out[s_garr[b] + (i - s_hist[b])] = s_ev[i];
    }
}

// ---------------- build pass B: per-bucket counting sort (in-place via LDS) + row_ptr ----------------

__global__ void sort4(int2* e0, int2* e1, int2* e2, int2* e3,
                      const int* __restrict__ bbase, const int* __restrict__ bcount,
                      int* rp0, int* rp1, int* rp2, int* rp3) {
    __shared__ int s_cnt[SPAN_N];
    __shared__ int s_tmp[BS];
    __shared__ int2 s_ev[STAGE_B];
    int t = threadIdx.x;
    int p = blockIdx.x / NB;
    int b = blockIdx.x % NB;
    int2* ev = (p == 0) ? e0 : (p == 1) ? e1 : (p == 2) ? e2 : e3;
    int* rp  = (p == 0) ? rp0 : (p == 1) ? rp1 : (p == 2) ? rp2 : rp3;
    int SH = prob_sh(p);
    int n = prob_n(p);
    int base = bbase[p * NB_MAX + b];
    int cnt  = bcount[p * NB_MAX + b];
    int kb = b << SH;
    int span = min(1 << SH, n - kb);
    for (int k = t; k < span; k += BS) s_cnt[k] = 0;
    __syncthreads();
    for (int i = t; i < cnt; i += BS)
        atomicAdd(&s_cnt[ev[base + i].x >> 18], 1);
    __syncthreads();
    // scan span (<=512): 2 elems/thread -> exclusive starts back into s_cnt
    int i0 = 2 * t, i1 = 2 * t + 1;
    int c0 = (i0 < span) ? s_cnt[i0] : 0;
    int c1 = (i1 < span) ? s_cnt[i1] : 0;
    int s = c0 + c1;
    s_tmp[t] = s;
    __syncthreads();
    for (int off = 1; off < BS; off <<= 1) {
        int v = (t >= off) ? s_tmp[t - off] : 0;
        __syncthreads();
        s_tmp[t] += v;
        __syncthreads();
    }
    int ex = s_tmp[t] - s;
    __syncthreads();
    if (i0 < span) { rp[kb + i0] = base + ex; s_cnt[i0] = ex; ex += c0; }
    if (i1 < span) { rp[kb + i1] = base + ex; s_cnt[i1] = ex; }
    if (b == NB - 1 && t == 0) rp[n] = NNZ;
    __syncthreads();
    for (int i = t; i < cnt; i += BS) {
        int2 e = ev[base + i];
        int r = atomicAdd(&s_cnt[e.x >> 18], 1);
        if (r < STAGE_B) s_ev[r] = make_int2(e.x & OTHER_MASK, e.y);
    }
    __syncthreads();
    int lim = min(cnt, STAGE_B);
    for (int i = t; i < lim; i += BS) ev[base + i] = s_ev[i];
}

// ---------------- fp32 -> fp16 convert ----------------

__global__ void f32_to_h(const float* __restrict__ src, __half* __restrict__ dst, int n4) {
    int i = blockIdx.x * BS + threadIdx.x;
    if (i < n4) {
        float4 f = ((const float4*)src)[i];
        __half2* d = (__half2*)dst + (size_t)i * 2;
        d[0] = __floats2half2_rn(f.x, f.y);
        d[1] = __floats2half2_rn(f.z, f.w);
    }
}

// ---------------- SpMM: quarter-wave (16 lanes, uint2) per row, fp32 accum, 8-deep unroll ----------------

__global__ __launch_bounds__(BS)
void spmm_h_kernel(const int* __restrict__ row_ptr, const int2* __restrict__ ev,
                   const uint2* __restrict__ x, uint2* __restrict__ y, int n_rows) {
    int row = blockIdx.x * 16 + (threadIdx.x >> 4);
    int l = threadIdx.x & 15;
    if (row >= n_rows) return;
    int p0 = row_ptr[row];
    int p1 = row_ptr[row + 1];
    float a0 = 0.f, a1 = 0.f, a2 = 0.f, a3 = 0.f;
    int j = p0;
#define ACC(g, v) {                                                   \
        __half2 hA = *(__half2*)&(g).x;                               \
        __half2 hB = *(__half2*)&(g).y;                               \
        float2 fA = __half22float2(hA);                               \
        float2 fB = __half22float2(hB);                               \
        a0 = fmaf((v), fA.x, a0); a1 = fmaf((v), fA.y, a1);           \
        a2 = fmaf((v), fB.x, a2); a3 = fmaf((v), fB.y, a3);           \
    }
    for (; j + 8 <= p1; j += 8) {
        int2 e[8];
        uint2 g[8];
#pragma unroll
        for (int k = 0; k < 8; ++k) e[k] = ev[j + k];
#pragma unroll
        for (int k = 0; k < 8; ++k) g[k] = x[(e[k].x << 4) + l];
#pragma unroll
        for (int k = 0; k < 8; ++k) ACC(g[k], __int_as_float(e[k].y));
    }
    for (; j + 2 <= p1; j += 2) {
        int2 e0 = ev[j + 0];
        int2 e1 = ev[j + 1];
        uint2 g0 = x[(e0.x << 4) + l];
        uint2 g1 = x[(e1.x << 4) + l];
        ACC(g0, __int_as_float(e0.y));
        ACC(g1, __int_as_float(e1.y));
    }
    for (; j < p1; ++j) {
        int2 e = ev[j];
        uint2 g = x[(e.x << 4) + l];
        ACC(g, __int_as_float(e.y));
    }
#undef ACC
    uint2 o;
    __half2 oA = __floats2half2_rn(a0, a1);
    __half2 oB = __floats2half2_rn(a2, a3);
    o.x = *(unsigned int*)&oA;
    o.y = *(unsigned int*)&oB;
    y[(row << 4) + l] = o;
}

// ---------------- fused leaky_relu + LayerNorm + residual (fp16 h) ----------------

__global__ void fused_ln_h(const __half* h, const float* __restrict__ embs,
                           const float* __restrict__ gamma, const float* __restrict__ beta,
                           __half* xh_out, float* f_out, int apply_leaky) {
    int row = blockIdx.x * 4 + (threadIdx.x >> 6);
    int lane = threadIdx.x & 63;
    if (row >= N_NODES) return;
    float v = __half2float(h[(row << 6) + lane]);
    if (apply_leaky) v = (v > 0.f) ? v : 0.2f * v;
    float s = v;
    for (int off = 32; off > 0; off >>= 1) s += __shfl_xor(s, off, 64);
    float mu = s * (1.0f / D);
    float dd = v - mu;
    float q = dd * dd;
    for (int off = 32; off > 0; off >>= 1) q += __shfl_xor(q, off, 64);
    float var = q * (1.0f / D);
    float res = dd * rsqrtf(var + 1e-5f) * gamma[lane] + beta[lane] + embs[(row << 6) + lane];
    if (xh_out) xh_out[(row << 6) + lane] = __float2half(res);
    else f_out[(row << 6) + lane] = res;
}

// ---------------- fallback: COO atomic SpMM + fp32 LN (used only if ws too small) ----------------

__global__ void spmm_atomic_kernel(const int* __restrict__ keys, const int* __restrict__ other,
                                   const float* __restrict__ vals, const float* __restrict__ x,
                                   float* __restrict__ y) {
    long i = (long)blockIdx.x * 256 + threadIdx.x;
    int e = (int)(i >> 4);
    int sub = ((int)i & 15) * 4;
    if (e >= NNZ) return;
    int r = keys[e];
    int c = other[e];
    float v = vals[e];
    const float4 xv = *(const float4*)&x[c * D + sub];
    atomicAdd(&y[r * D + sub + 0], v * xv.x);
    atomicAdd(&y[r * D + sub + 1], v * xv.y);
    atomicAdd(&y[r * D + sub + 2], v * xv.z);
    atomicAdd(&y[r * D + sub + 3], v * xv.w);
}

__global__ void fused_ln_kernel(float* __restrict__ h, const float* __restrict__ embs,
                                const float* __restrict__ gamma, const float* __restrict__ beta,
                                int n_rows, int apply_leaky) {
    int row = blockIdx.x * 4 + (threadIdx.x >> 6);
    int lane = threadIdx.x & 63;
    if (row >= n_rows) return;
    float v = h[row * D + lane];
    if (apply_leaky) v = (v > 0.f) ? v : 0.2f * v;
    float s = v;
    for (int off = 32; off > 0; off >>= 1) s += __shfl_xor(s, off, 64);
    float mu = s * (1.0f / D);
    float dd = v - mu;
    float q = dd * dd;
    for (int off = 32; off > 0; off >>= 1) q += __shfl_xor(q, off, 64);
    float var = q * (1.0f / D);
    h[row * D + lane] = dd * rsqrtf(var + 1e-5f) * gamma[lane] + beta[lane]
                        + embs[row * D + lane];
}

extern "C" void kernel_launch(void* const* d_in, const int* in_sizes, int n_in,
                              void* d_out, int out_size, void* d_ws, size_t ws_size,
                              hipStream_t stream) {
    const float* embs   = (const float*)d_in[0];
    const int*   A_rows = (const int*)d_in[1];
    const int*   A_cols = (const int*)d_in[2];
    const float* A_vals = (const float*)d_in[3];
    const int*   S_rows = (const int*)d_in[4];
    const int*   S_cols = (const int*)d_in[5];
    const float* S_vals = (const float*)d_in[6];
    const float* gamma  = (const float*)d_in[7];   // [2][64]
    const float* beta   = (const float*)d_in[8];   // [2][64]
    float* out = (float*)d_out;

    // ---- workspace layout ----
    size_t off = 0;
    auto bump = [&](size_t b) { size_t o = off; off += (b + 255) & ~(size_t)255; return o; };
    size_t o_xh   = bump((size_t)N_NODES * D * 2);   // x fp16; also h (t4)
    size_t o_th   = bump((size_t)N_NODES * D * 2);   // t1/t3 fp16
    size_t o_tHh  = bump((size_t)H_EDGES * D * 2);   // t2 fp16
    size_t o_ev[4];
    for (int i = 0; i < 4; ++i) o_ev[i] = bump((size_t)NNZ * 8);
    size_t o_rpAT = bump((size_t)(N_NODES + 1) * 4);
    size_t o_rpST = bump((size_t)(H_EDGES + 1) * 4);
    size_t o_rpS  = bump((size_t)(N_NODES + 1) * 4);
    size_t o_rpA  = bump((size_t)(N_NODES + 1) * 4);
    size_t o_bcount = bump((size_t)4 * NB_MAX * 4);
    size_t o_bbase  = bump((size_t)4 * NB_MAX * 4);
    size_t o_gcur   = bump((size_t)4 * NB_MAX * 4);
    size_t needed_csr = off;

    char* w = (char*)d_ws;
    __half* xh  = (__half*)(w + o_xh);
    __half* th  = (__half*)(w + o_th);
    __half* tHh = (__half*)(w + o_tHh);
    __half* hh  = xh;                               // h aliases x (safe by schedule)
    int2* evb[4];
    for (int i = 0; i < 4; ++i) evb[i] = (int2*)(w + o_ev[i]);
    int* rpAT = (int*)(w + o_rpAT);
    int* rpST = (int*)(w + o_rpST);
    int* rpS  = (int*)(w + o_rpS);
    int* rpA  = (int*)(w + o_rpA);
    int* bcount = (int*)(w + o_bcount);
    int* bbase  = (int*)(w + o_bbase);
    int* gcur   = (int*)(w + o_gcur);

    bool use_csr = (ws_size >= needed_csr);

    if (use_csr) {
        // ---- unified build (4 sorts, 5 launches) ----
        hipMemsetAsync(bcount, 0, (size_t)4 * NB_MAX * 4, stream);
        hist4<<<4 * NBLK, BS, 0, stream>>>(A_cols, S_cols, S_rows, A_rows, bcount);
        spine4<<<4, BS, 0, stream>>>(bcount, bbase, gcur);
        scatter4<<<4 * NBLK, BS, 0, stream>>>(A_cols, A_rows, A_vals,
                                              S_cols, S_rows, S_vals,
                                              S_rows, S_cols, S_vals,
                                              A_rows, A_cols, A_vals,
                                              gcur,
                                              evb[0], evb[1], evb[2], evb[3]);
        sort4<<<4 * NB, BS, 0, stream>>>(evb[0], evb[1], evb[2], evb[3],
                                         bbase, bcount, rpAT, rpST, rpS, rpA);

        // ---- embs -> fp16 ----
        int n4 = N_NODES * D / 4;
        f32_to_h<<<(n4 + BS - 1) / BS, BS, 0, stream>>>(embs, xh, n4);

        auto spmm = [&](int* rp, int2* ev, const __half* x, __half* y, int n) {
            spmm_h_kernel<<<(n + 15) / 16, BS, 0, stream>>>(rp, ev, (const uint2*)x,
                                                            (uint2*)y, n);
        };

        for (int layer = 0; layer < 2; ++layer) {
            spmm(rpAT, evb[0], xh,  th,  N_NODES);   // t1 = A^T x   [N]  (xh dead after)
            spmm(rpST, evb[1], th,  tHh, H_EDGES);   // t2 = S^T t1  [H]
            spmm(rpS,  evb[2], tHh, th,  N_NODES);   // t3 = S t2    [N]
            spmm(rpA,  evb[3], th,  hh,  N_NODES);   // t4 = A t3    [N]  (hh == xh)
            if (layer == 0)
                fused_ln_h<<<(N_NODES + 3) / 4, BS, 0, stream>>>(
                    hh, embs, gamma, beta, xh, nullptr, 1);
            else
                fused_ln_h<<<(N_NODES + 3) / 4, BS, 0, stream>>>(
                    hh, embs, gamma + D, beta + D, nullptr, out, 0);
        }
    } else {
        // COO + atomics fallback (needs only 64 MB)
        float* B1 = (float*)w;
        float* BH = (float*)(w + (size_t)N_NODES * D * 4);
        auto spmm_at = [&](const int* keys, const int* other, const float* vals,
                           const float* x, float* y, int n) {
            hipMemsetAsync(y, 0, (size_t)n * D * 4, stream);
            long threads = (long)NNZ * 16;
            int blocks = (int)((threads + 255) / 256);
            spmm_atomic_kernel<<<blocks, 256, 0, stream>>>(keys, other, vals, x, y);
        };
        for (int layer = 0; layer < 2; ++layer) {
            const float* xin = (layer == 0) ? embs : out;
            spmm_at(A_cols, A_rows, A_vals, xin, B1, N_NODES);
            spmm_at(S_cols, S_rows, S_vals, B1,  BH, H_EDGES);
            spmm_at(S_rows, S_cols, S_vals, BH,  B1, N_NODES);
            spmm_at(A_rows, A_cols, A_vals, B1,  out, N_NODES);
            fused_ln_kernel<<<(N_NODES + 3) / 4, 256, 0, stream>>>(
                out, embs, gamma + layer * D, beta + layer * D, N_NODES, layer == 0 ? 1 : 0);
        }
    }
}

// Round 7
// 556.921 us; speedup vs baseline: 4.3667x; 1.0954x over previous
//
#include <hip/hip_runtime.h>
#include <hip/hip_fp16.h>

#define N_NODES 200000
#define H_EDGES 50000
#define D 64
#define NNZ 2000000

#define BS 256
#define EPB 24
#define EDGES_PER_BLOCK (EPB * BS)                            // 6144
#define NBLK ((NNZ + EDGES_PER_BLOCK - 1) / EDGES_PER_BLOCK)  // 326
#define NB 391        // ceil(200000/512) == ceil(50000/128) == 391
#define NB_MAX 392
#define SPAN_N 512
#define CAP 6144      // fixed per-bucket capacity (mean 5115, sigma ~72 -> 14 sigma headroom)
#define OTHER_MASK 0x3FFFF

// problem p: 0 = A^T (keys A_cols, SH=9), 1 = S^T (keys S_cols, SH=7), 2 = S (S_rows), 3 = A (A_rows)
__device__ __forceinline__ int prob_sh(int p) { return (p == 1) ? 7 : 9; }
__device__ __forceinline__ int prob_n(int p)  { return (p == 1) ? H_EDGES : N_NODES; }

// ---------------- build init: fixed bucket bases ----------------

__global__ void init_gcur(int* __restrict__ gcur) {
    int i = blockIdx.x * BS + threadIdx.x;
    if (i < 4 * NB_MAX) {
        int b = i % NB_MAX;
        gcur[i] = (b < NB) ? b * CAP : NB * CAP;
    }
}

// ---------------- build pass A: LDS-staged bucket scatter -> packed int2 ----------------
// packed entry: .x = other | (key_in_bucket << 18), .y = val bits

__global__ __launch_bounds__(BS, 2)
void scatter4(const int* k0, const int* o0, const float* v0_,
              const int* k1, const int* o1, const float* v1_,
              const int* k2, const int* o2, const float* v2_,
              const int* k3, const int* o3, const float* v3_,
              int* __restrict__ gcur,
              int2* e0, int2* e1, int2* e2, int2* e3) {
    __shared__ int s_hist[NB_MAX];
    __shared__ int s_garr[NB_MAX];
    __shared__ int s_tmp[BS];
    __shared__ int2 s_ev[EDGES_PER_BLOCK];
    __shared__ unsigned short s_bkt[EDGES_PER_BLOCK];
    int t = threadIdx.x;
    int p = blockIdx.x / NBLK;
    int lb = blockIdx.x % NBLK;
    const int*   keys  = (p == 0) ? k0 : (p == 1) ? k1 : (p == 2) ? k2 : k3;
    const int*   other = (p == 0) ? o0 : (p == 1) ? o1 : (p == 2) ? o2 : o3;
    const float* vals  = (p == 0) ? v0_ : (p == 1) ? v1_ : (p == 2) ? v2_ : v3_;
    int2* ev_out = (p == 0) ? e0 : (p == 1) ? e1 : (p == 2) ? e2 : e3;
    int SH = prob_sh(p);
    int KM = (1 << SH) - 1;
    int* gc = gcur + p * NB_MAX;

    int blkbase = lb * EDGES_PER_BLOCK;
    int tot = min(EDGES_PER_BLOCK, NNZ - blkbase);
    for (int i = t; i < NB; i += BS) s_hist[i] = 0;
    __syncthreads();
    int bkt[EPB], meta[EPB];   // meta = rank | (klo<<13)
#pragma unroll
    for (int k = 0; k < EPB; ++k) {
        int e = blkbase + k * BS + t;
        if (e < NNZ) {
            int key = keys[e];
            int b = key >> SH;
            bkt[k] = b;
            meta[k] = atomicAdd(&s_hist[b], 1) | ((key & KM) << 13);
        } else bkt[k] = -1;
    }
    __syncthreads();
    // exclusive scan of s_hist -> local starts; reserve global ranges (2 elems/thread)
    int i0 = 2 * t, i1 = 2 * t + 1;
    int c0 = (i0 < NB) ? s_hist[i0] : 0;
    int c1 = (i1 < NB) ? s_hist[i1] : 0;
    int ssum = c0 + c1;
    s_tmp[t] = ssum;
    __syncthreads();
    for (int off = 1; off < BS; off <<= 1) {
        int v = (t >= off) ? s_tmp[t - off] : 0;
        __syncthreads();
        s_tmp[t] += v;
        __syncthreads();
    }
    int ebase = s_tmp[t] - ssum;
    if (i0 < NB) {
        s_hist[i0] = ebase;
        if (c0 > 0) s_garr[i0] = atomicAdd(&gc[i0], c0);
        ebase += c0;
    }
    if (i1 < NB) {
        s_hist[i1] = ebase;
        if (c1 > 0) s_garr[i1] = atomicAdd(&gc[i1], c1);
    }
    __syncthreads();
    // stage packed edges grouped by bucket
#pragma unroll
    for (int k = 0; k < EPB; ++k) {
        if (bkt[k] < 0) continue;
        int e = blkbase + k * BS + t;
        int rnk = meta[k] & 0x1FFF;
        int klo = meta[k] >> 13;
        int pos = s_hist[bkt[k]] + rnk;
        s_ev[pos] = make_int2(other[e] | (klo << 18), __float_as_int(vals[e]));
        s_bkt[pos] = (unsigned short)bkt[k];
    }
    __syncthreads();
    for (int i = t; i < tot; i += BS) {
        int b = s_bkt[i];
        ev_out[s_garr[b] + (i - s_hist[b])] = s_ev[i];
    }
}

// ---------------- build pass B: per-bucket counting sort + int2 row ranges ----------------

__global__ void sort4(int2* e0, int2* e1, int2* e2, int2* e3,
                      const int* __restrict__ gcur,
                      int2* rp0, int2* rp1, int2* rp2_, int2* rp3) {
    __shared__ int s_cnt[SPAN_N];
    __shared__ int s_tmp[BS];
    __shared__ int2 s_ev[CAP];
    int t = threadIdx.x;
    int p = blockIdx.x / NB;
    int b = blockIdx.x % NB;
    int2* ev = (p == 0) ? e0 : (p == 1) ? e1 : (p == 2) ? e2 : e3;
    int2* rp = (p == 0) ? rp0 : (p == 1) ? rp1 : (p == 2) ? rp2_ : rp3;
    int SH = prob_sh(p);
    int n = prob_n(p);
    int base = b * CAP;
    int cnt  = gcur[p * NB_MAX + b] - base;
    int kb = b << SH;
    int span = min(1 << SH, n - kb);
    for (int k = t; k < span; k += BS) s_cnt[k] = 0;
    __syncthreads();
    for (int i = t; i < cnt; i += BS)
        atomicAdd(&s_cnt[ev[base + i].x >> 18], 1);
    __syncthreads();
    // scan span (<=512): 2 elems/thread -> exclusive starts back into s_cnt
    int i0 = 2 * t, i1 = 2 * t + 1;
    int c0 = (i0 < span) ? s_cnt[i0] : 0;
    int c1 = (i1 < span) ? s_cnt[i1] : 0;
    int s = c0 + c1;
    s_tmp[t] = s;
    __syncthreads();
    for (int off = 1; off < BS; off <<= 1) {
        int v = (t >= off) ? s_tmp[t - off] : 0;
        __syncthreads();
        s_tmp[t] += v;
        __syncthreads();
    }
    int ex = s_tmp[t] - s;
    __syncthreads();
    if (i0 < span) { rp[kb + i0] = make_int2(base + ex, base + ex + c0); s_cnt[i0] = ex; ex += c0; }
    if (i1 < span) { rp[kb + i1] = make_int2(base + ex, base + ex + c1); s_cnt[i1] = ex; }
    __syncthreads();
    for (int i = t; i < cnt; i += BS) {
        int2 e = ev[base + i];
        int r = atomicAdd(&s_cnt[e.x >> 18], 1);
        s_ev[r] = make_int2(e.x & OTHER_MASK, e.y);
    }
    __syncthreads();
    for (int i = t; i < cnt; i += BS) ev[base + i] = s_ev[i];
}

// ---------------- fp32 -> fp16 convert ----------------

__global__ void f32_to_h(const float* __restrict__ src, __half* __restrict__ dst, int n4) {
    int i = blockIdx.x * BS + threadIdx.x;
    if (i < n4) {
        float4 f = ((const float4*)src)[i];
        __half2* d = (__half2*)dst + (size_t)i * 2;
        d[0] = __floats2half2_rn(f.x, f.y);
        d[1] = __floats2half2_rn(f.z, f.w);
    }
}

// ---------------- SpMM: quarter-wave (16 lanes, uint2) per row, fp32 accum, 8-deep unroll ----------------

__global__ __launch_bounds__(BS)
void spmm_h_kernel(const int2* __restrict__ rp, const int2* __restrict__ ev,
                   const uint2* __restrict__ x, uint2* __restrict__ y, int n_rows) {
    int row = blockIdx.x * 16 + (threadIdx.x >> 4);
    int l = threadIdx.x & 15;
    if (row >= n_rows) return;
    int2 pr = rp[row];
    int p0 = pr.x;
    int p1 = pr.y;
    float a0 = 0.f, a1 = 0.f, a2 = 0.f, a3 = 0.f;
    int j = p0;
#define ACC(g, v) {                                                   \
        __half2 hA = *(__half2*)&(g).x;                               \
        __half2 hB = *(__half2*)&(g).y;                               \
        float2 fA = __half22float2(hA);                               \
        float2 fB = __half22float2(hB);                               \
        a0 = fmaf((v), fA.x, a0); a1 = fmaf((v), fA.y, a1);           \
        a2 = fmaf((v), fB.x, a2); a3 = fmaf((v), fB.y, a3);           \
    }
    for (; j + 8 <= p1; j += 8) {
        int2 e[8];
        uint2 g[8];
#pragma unroll
        for (int k = 0; k < 8; ++k) e[k] = ev[j + k];
#pragma unroll
        for (int k = 0; k < 8; ++k) g[k] = x[(e[k].x << 4) + l];
#pragma unroll
        for (int k = 0; k < 8; ++k) ACC(g[k], __int_as_float(e[k].y));
    }
    for (; j + 2 <= p1; j += 2) {
        int2 e0 = ev[j + 0];
        int2 e1 = ev[j + 1];
        uint2 g0 = x[(e0.x << 4) + l];
        uint2 g1 = x[(e1.x << 4) + l];
        ACC(g0, __int_as_float(e0.y));
        ACC(g1, __int_as_float(e1.y));
    }
    for (; j < p1; ++j) {
        int2 e = ev[j];
        uint2 g = x[(e.x << 4) + l];
        ACC(g, __int_as_float(e.y));
    }
#undef ACC
    uint2 o;
    __half2 oA = __floats2half2_rn(a0, a1);
    __half2 oB = __floats2half2_rn(a2, a3);
    o.x = *(unsigned int*)&oA;
    o.y = *(unsigned int*)&oB;
    y[(row << 4) + l] = o;
}

// ---------------- fused leaky_relu + LayerNorm + residual (fp16 h) ----------------

__global__ void fused_ln_h(const __half* h, const float* __restrict__ embs,
                           const float* __restrict__ gamma, const float* __restrict__ beta,
                           __half* xh_out, float* f_out, int apply_leaky) {
    int row = blockIdx.x * 4 + (threadIdx.x >> 6);
    int lane = threadIdx.x & 63;
    if (row >= N_NODES) return;
    float v = __half2float(h[(row << 6) + lane]);
    if (apply_leaky) v = (v > 0.f) ? v : 0.2f * v;
    float s = v;
    for (int off = 32; off > 0; off >>= 1) s += __shfl_xor(s, off, 64);
    float mu = s * (1.0f / D);
    float dd = v - mu;
    float q = dd * dd;
    for (int off = 32; off > 0; off >>= 1) q += __shfl_xor(q, off, 64);
    float var = q * (1.0f / D);
    float res = dd * rsqrtf(var + 1e-5f) * gamma[lane] + beta[lane] + embs[(row << 6) + lane];
    if (xh_out) xh_out[(row << 6) + lane] = __float2half(res);
    else f_out[(row << 6) + lane] = res;
}

// ---------------- fallback: COO atomic SpMM + fp32 LN (used only if ws too small) ----------------

__global__ void spmm_atomic_kernel(const int* __restrict__ keys, const int* __restrict__ other,
                                   const float* __restrict__ vals, const float* __restrict__ x,
                                   float* __restrict__ y) {
    long i = (long)blockIdx.x * 256 + threadIdx.x;
    int e = (int)(i >> 4);
    int sub = ((int)i & 15) * 4;
    if (e >= NNZ) return;
    int r = keys[e];
    int c = other[e];
    float v = vals[e];
    const float4 xv = *(const float4*)&x[c * D + sub];
    atomicAdd(&y[r * D + sub + 0], v * xv.x);
    atomicAdd(&y[r * D + sub + 1], v * xv.y);
    atomicAdd(&y[r * D + sub + 2], v * xv.z);
    atomicAdd(&y[r * D + sub + 3], v * xv.w);
}

__global__ void fused_ln_kernel(float* __restrict__ h, const float* __restrict__ embs,
                                const float* __restrict__ gamma, const float* __restrict__ beta,
                                int n_rows, int apply_leaky) {
    int row = blockIdx.x * 4 + (threadIdx.x >> 6);
    int lane = threadIdx.x & 63;
    if (row >= n_rows) return;
    float v = h[row * D + lane];
    if (apply_leaky) v = (v > 0.f) ? v : 0.2f * v;
    float s = v;
    for (int off = 32; off > 0; off >>= 1) s += __shfl_xor(s, off, 64);
    float mu = s * (1.0f / D);
    float dd = v - mu;
    float q = dd * dd;
    for (int off = 32; off > 0; off >>= 1) q += __shfl_xor(q, off, 64);
    float var = q * (1.0f / D);
    h[row * D + lane] = dd * rsqrtf(var + 1e-5f) * gamma[lane] + beta[lane]
                        + embs[row * D + lane];
}

extern "C" void kernel_launch(void* const* d_in, const int* in_sizes, int n_in,
                              void* d_out, int out_size, void* d_ws, size_t ws_size,
                              hipStream_t stream) {
    const float* embs   = (const float*)d_in[0];
    const int*   A_rows = (const int*)d_in[1];
    const int*   A_cols = (const int*)d_in[2];
    const float* A_vals = (const float*)d_in[3];
    const int*   S_rows = (const int*)d_in[4];
    const int*   S_cols = (const int*)d_in[5];
    const float* S_vals = (const float*)d_in[6];
    const float* gamma  = (const float*)d_in[7];   // [2][64]
    const float* beta   = (const float*)d_in[8];   // [2][64]
    float* out = (float*)d_out;

    // ---- workspace layout ----
    size_t off = 0;
    auto bump = [&](size_t b) { size_t o = off; off += (b + 255) & ~(size_t)255; return o; };
    size_t o_xh   = bump((size_t)N_NODES * D * 2);   // x fp16; also h (t4)
    size_t o_th   = bump((size_t)N_NODES * D * 2);   // t1/t3 fp16
    size_t o_tHh  = bump((size_t)H_EDGES * D * 2);   // t2 fp16
    size_t o_ev[4];
    for (int i = 0; i < 4; ++i) o_ev[i] = bump((size_t)NB * CAP * 8);
    size_t o_rpAT = bump((size_t)N_NODES * 8);
    size_t o_rpST = bump((size_t)H_EDGES * 8);
    size_t o_rpS  = bump((size_t)N_NODES * 8);
    size_t o_rpA  = bump((size_t)N_NODES * 8);
    size_t o_gcur = bump((size_t)4 * NB_MAX * 4);
    size_t needed_csr = off;

    char* w = (char*)d_ws;
    __half* xh  = (__half*)(w + o_xh);
    __half* th  = (__half*)(w + o_th);
    __half* tHh = (__half*)(w + o_tHh);
    __half* hh  = xh;                               // h aliases x (safe by schedule)
    int2* evb[4];
    for (int i = 0; i < 4; ++i) evb[i] = (int2*)(w + o_ev[i]);
    int2* rpAT = (int2*)(w + o_rpAT);
    int2* rpST = (int2*)(w + o_rpST);
    int2* rpS  = (int2*)(w + o_rpS);
    int2* rpA  = (int2*)(w + o_rpA);
    int* gcur  = (int*)(w + o_gcur);

    bool use_csr = (ws_size >= needed_csr);

    if (use_csr) {
        // ---- unified build (3 launches) ----
        init_gcur<<<(4 * NB_MAX + BS - 1) / BS, BS, 0, stream>>>(gcur);
        scatter4<<<4 * NBLK, BS, 0, stream>>>(A_cols, A_rows, A_vals,
                                              S_cols, S_rows, S_vals,
                                              S_rows, S_cols, S_vals,
                                              A_rows, A_cols, A_vals,
                                              gcur,
                                              evb[0], evb[1], evb[2], evb[3]);
        sort4<<<4 * NB, BS, 0, stream>>>(evb[0], evb[1], evb[2], evb[3],
                                         gcur, rpAT, rpST, rpS, rpA);

        // ---- embs -> fp16 ----
        int n4 = N_NODES * D / 4;
        f32_to_h<<<(n4 + BS - 1) / BS, BS, 0, stream>>>(embs, xh, n4);

        auto spmm = [&](int2* rp, int2* ev, const __half* x, __half* y, int n) {
            spmm_h_kernel<<<(n + 15) / 16, BS, 0, stream>>>(rp, ev, (const uint2*)x,
                                                            (uint2*)y, n);
        };

        for (int layer = 0; layer < 2; ++layer) {
            spmm(rpAT, evb[0], xh,  th,  N_NODES);   // t1 = A^T x   [N]  (xh dead after)
            spmm(rpST, evb[1], th,  tHh, H_EDGES);   // t2 = S^T t1  [H]
            spmm(rpS,  evb[2], tHh, th,  N_NODES);   // t3 = S t2    [N]
            spmm(rpA,  evb[3], th,  hh,  N_NODES);   // t4 = A t3    [N]  (hh == xh)
            if (layer == 0)
                fused_ln_h<<<(N_NODES + 3) / 4, BS, 0, stream>>>(
                    hh, embs, gamma, beta, xh, nullptr, 1);
            else
                fused_ln_h<<<(N_NODES + 3) / 4, BS, 0, stream>>>(
                    hh, embs, gamma + D, beta + D, nullptr, out, 0);
        }
    } else {
        // COO + atomics fallback (needs only 64 MB)
        float* B1 = (float*)w;
        float* BH = (float*)(w + (size_t)N_NODES * D * 4);
        auto spmm_at = [&](const int* keys, const int* other, const float* vals,
                           const float* x, float* y, int n) {
            hipMemsetAsync(y, 0, (size_t)n * D * 4, stream);
            long threads = (long)NNZ * 16;
            int blocks = (int)((threads + 255) / 256);
            spmm_atomic_kernel<<<blocks, 256, 0, stream>>>(keys, other, vals, x, y);
        };
        for (int layer = 0; layer < 2; ++layer) {
            const float* xin = (layer == 0) ? embs : out;
            spmm_at(A_cols, A_rows, A_vals, xin, B1, N_NODES);
            spmm_at(S_cols, S_rows, S_vals, B1,  BH, H_EDGES);
            spmm_at(S_rows, S_cols, S_vals, BH,  B1, N_NODES);
            spmm_at(A_rows, A_cols, A_vals, B1,  out, N_NODES);
            fused_ln_kernel<<<(N_NODES + 3) / 4, 256, 0, stream>>>(
                out, embs, gamma + layer * D, beta + layer * D, N_NODES, layer == 0 ? 1 : 0);
        }
    }
}